// Round 8
// baseline (1048.202 us; speedup 1.0000x reference)
//
#include <hip/hip_runtime.h>
#include <hip/hip_bf16.h>

#define NN 50000
#define NE 800000
#define NG 512
#define DD 128
#define MM 256
#define TT 4
#define NPASS 4
#define GHID 256
#define NKEY (NN * TT)          // CSR keys: src*4 + type

typedef __bf16 bf16x2 __attribute__((ext_vector_type(2)));
typedef __bf16 bf16x4 __attribute__((ext_vector_type(4)));
typedef __bf16 bf16x8 __attribute__((ext_vector_type(8)));
typedef float f32x4 __attribute__((ext_vector_type(4)));

__device__ __forceinline__ float fast_sigmoid(float x) {
    return __builtin_amdgcn_rcpf(1.f + __expf(-x));
}
__device__ __forceinline__ float fast_tanh(float x) {
    float e2 = __expf(2.f * x);
    return 1.f - 2.f * __builtin_amdgcn_rcpf(e2 + 1.f);
}

#define GLDS(SRC, DST) \
    __builtin_amdgcn_global_load_lds( \
        (const __attribute__((address_space(1))) unsigned int*)(SRC), \
        (__attribute__((address_space(3))) unsigned int*)(DST), 16, 0, 0)

// ================= setup: swizzled weights =================
__global__ void build_WK(const float* __restrict__ W_msg, __bf16* __restrict__ WK) {
    int i = blockIdx.x * 256 + threadIdx.x;           // 131072
    if (i >= 16 * 4 * 256 * 8) return;
    int j = i & 7, col = (i >> 3) & 255, g = i >> 11; // g=c*4+lq
    int k = g * 8 + j;
    WK[i] = (__bf16)W_msg[k * 256 + col];
}

// j-major GRU weight layout: WBj[j][c][lq][gate][lm][e]
// value = B[k=(c*4+lq)*8+e][col = gate*128 + j*16 + lm]
__global__ void build_WBj(const float* __restrict__ W_ih, const float* __restrict__ W_hh,
                          __bf16* __restrict__ WB) {
    int i = blockIdx.x * 256 + threadIdx.x;           // 196608
    if (i >= 8 * 12 * 4 * 4 * 16 * 8) return;
    int low = i & 127;
    int lm = low >> 3, e = low & 7;
    int rest = i >> 7;
    int g  = rest & 3;
    int lq = (rest >> 2) & 3;
    int jc = rest >> 4;          // j*12 + c
    int c  = jc % 12;
    int j  = jc / 12;
    int k   = (c * 4 + lq) * 8 + e;     // 0..383
    int col = g * 128 + j * 16 + lm;    // 0..511
    float v = 0.f;
    if (col < 256) {
        v = (k < 256) ? W_ih[col * 256 + k] : W_hh[col * 128 + (k - 256)];
    } else if (col < 384) {
        if (k < 256) v = W_ih[col * 256 + k];
    } else {
        if (k >= 256) v = W_hh[(col - 128) * 128 + (k - 256)];
    }
    WB[i] = (__bf16)v;
}

__global__ void build_bias512(const float* __restrict__ b_ih, const float* __restrict__ b_hh,
                              float* __restrict__ b512) {
    int c = blockIdx.x * 256 + threadIdx.x;
    if (c >= 512) return;
    float v;
    if (c < 256) v = b_ih[c] + b_hh[c];
    else if (c < 384) v = b_ih[c];
    else v = b_hh[c - 128];
    b512[c] = v;
}

// ================= embedding =================
__global__ void embed_kernel(const int* __restrict__ node_types,
                             const float* __restrict__ emb,
                             float* __restrict__ hf, __bf16* __restrict__ Acat,
                             __bf16* __restrict__ hbc) {
    int t = blockIdx.x * 256 + threadIdx.x;
    if (t >= NN * DD) return;
    int node = t >> 7, d = t & 127;
    float v = emb[node_types[node] * DD + d];
    hf[t] = v;
    __bf16 b = (__bf16)v;
    Acat[(size_t)node * 384 + 256 + d] = b;
    hbc[t] = b;
}

// ================= CSR build (keyed by src*4+type) =================
__global__ void hist_kernel(const int* __restrict__ src, const int* __restrict__ et,
                            int* __restrict__ counts) {
    int e = blockIdx.x * 256 + threadIdx.x;
    if (e < NE) atomicAdd(&counts[src[e] * TT + et[e]], 1);
}

__global__ void ghist_kernel(const int* __restrict__ n2g, int* __restrict__ gcounts) {
    int i = blockIdx.x * 256 + threadIdx.x;
    if (i < NN) atomicAdd(&gcounts[n2g[i]], 1);
}

__global__ void scan1(const int* __restrict__ counts, int* __restrict__ offsets,
                      int* __restrict__ bsum, int n) {
    __shared__ int sm[256];
    int i = blockIdx.x * 256 + threadIdx.x;
    int v = (i < n) ? counts[i] : 0;
    sm[threadIdx.x] = v;
    __syncthreads();
    for (int off = 1; off < 256; off <<= 1) {
        int t = (threadIdx.x >= off) ? sm[threadIdx.x - off] : 0;
        __syncthreads();
        sm[threadIdx.x] += t;
        __syncthreads();
    }
    if (i < n) offsets[i] = sm[threadIdx.x] - v;
    if (threadIdx.x == 255) bsum[blockIdx.x] = sm[255];
}

__global__ void scan2(int* __restrict__ bsum, int nb, int* __restrict__ offsets, int n) {
    __shared__ int sm[1024];
    int v = (threadIdx.x < nb) ? bsum[threadIdx.x] : 0;
    sm[threadIdx.x] = v;
    __syncthreads();
    for (int off = 1; off < 1024; off <<= 1) {
        int t = (threadIdx.x >= off) ? sm[threadIdx.x - off] : 0;
        __syncthreads();
        sm[threadIdx.x] += t;
        __syncthreads();
    }
    if (threadIdx.x < nb) bsum[threadIdx.x] = sm[threadIdx.x] - v;
    if (threadIdx.x == 1023) offsets[n] = sm[1023];
}

__global__ void scan3(int* __restrict__ offsets, const int* __restrict__ bsum,
                      int* __restrict__ cursor, int n) {
    int i = blockIdx.x * 256 + threadIdx.x;
    if (i < n) {
        int o = offsets[i] + bsum[blockIdx.x];
        offsets[i] = o;
        if (cursor) cursor[i] = o;
    }
}

__global__ void fill_kernel(const int* __restrict__ src, const int* __restrict__ dst,
                            const int* __restrict__ et, int* __restrict__ cursor,
                            int* __restrict__ elist) {
    int e = blockIdx.x * 256 + threadIdx.x;
    if (e >= NE) return;
    int pos = atomicAdd(&cursor[src[e] * TT + et[e]], 1);
    elist[pos] = dst[e];
}

// ================= FUSED aggregation + msgs GEMM =================
// Block: 4 waves, 64 src rows. Per type-stage t: each wave gathers its 16 keys
// (row*4+t) into a wave-private Xs slab (XOR-swizzled), interleaved with the
// 16-chunk MFMA loop (gathers issued at c=0,4,8). Bs ping-pong as before.
__global__ __launch_bounds__(256, 2)
void agg_msgs(const int* __restrict__ offsets, const int* __restrict__ elist,
              const __bf16* __restrict__ hbc, const __bf16* __restrict__ WK,
              const float* __restrict__ b_msg, __bf16* __restrict__ Acat) {
    __shared__ __bf16 Bs[2][8192];       // 32 KB ping-pong (WK chunks)
    __shared__ __bf16 Xs[2][64 * 128];   // 32 KB double-buffer (per-type aggregates)
    int tid = threadIdx.x, lane = tid & 63;
    int wv = __builtin_amdgcn_readfirstlane(tid >> 6);
    int lm = lane & 15, lq = lane >> 4;
    int r0 = blockIdx.x * 64;
    int wr0 = r0 + wv * 16;              // this wave's 16 rows

    // gather type t into Xs[buf] (wave-private rows; no barrier needed)
    auto gather = [&](int t, int buf) {
        char* xbase = (char*)&Xs[buf][0] + wv * 4096;
        const __bf16* hb = hbc + lane * 2;
#pragma unroll 1
        for (int kk = 0; kk < 16; ++kk) {
            int row = wr0 + kk;
            float a0 = 0.f, b0 = 0.f, a1 = 0.f, b1 = 0.f;
            if (row < NN) {
                int key = row * TT + t;
                int beg = __builtin_amdgcn_readfirstlane(offsets[key]);
                int end = __builtin_amdgcn_readfirstlane(offsets[key + 1]);
                for (int base = beg; base < end; base += 8) {
                    int nb = end - base; if (nb > 8) nb = 8;   // wave-uniform
                    int e1 = end - 1;
                    int i0 = elist[base];
                    int i1 = elist[(base + 1 <= e1) ? base + 1 : e1];
                    int i2 = elist[(base + 2 <= e1) ? base + 2 : e1];
                    int i3 = elist[(base + 3 <= e1) ? base + 3 : e1];
                    int i4 = elist[(base + 4 <= e1) ? base + 4 : e1];
                    int i5 = elist[(base + 5 <= e1) ? base + 5 : e1];
                    int i6 = elist[(base + 6 <= e1) ? base + 6 : e1];
                    int i7 = elist[(base + 7 <= e1) ? base + 7 : e1];
                    bf16x2 v0, v1, v2, v3, v4, v5, v6, v7;
                    v0 = *(const bf16x2*)(hb + (size_t)i0 * DD);
                    if (nb > 1) v1 = *(const bf16x2*)(hb + (size_t)i1 * DD);
                    if (nb > 2) v2 = *(const bf16x2*)(hb + (size_t)i2 * DD);
                    if (nb > 3) v3 = *(const bf16x2*)(hb + (size_t)i3 * DD);
                    if (nb > 4) v4 = *(const bf16x2*)(hb + (size_t)i4 * DD);
                    if (nb > 5) v5 = *(const bf16x2*)(hb + (size_t)i5 * DD);
                    if (nb > 6) v6 = *(const bf16x2*)(hb + (size_t)i6 * DD);
                    if (nb > 7) v7 = *(const bf16x2*)(hb + (size_t)i7 * DD);
                    a0 += (float)v0.x; b0 += (float)v0.y;
                    if (nb > 1) { a1 += (float)v1.x; b1 += (float)v1.y; }
                    if (nb > 2) { a0 += (float)v2.x; b0 += (float)v2.y; }
                    if (nb > 3) { a1 += (float)v3.x; b1 += (float)v3.y; }
                    if (nb > 4) { a0 += (float)v4.x; b0 += (float)v4.y; }
                    if (nb > 5) { a1 += (float)v5.x; b1 += (float)v5.y; }
                    if (nb > 6) { a0 += (float)v6.x; b0 += (float)v6.y; }
                    if (nb > 7) { a1 += (float)v7.x; b1 += (float)v7.y; }
                }
            }
            bf16x2 o;
            o.x = (__bf16)(a0 + a1);
            o.y = (__bf16)(b0 + b1);
            *(bf16x2*)(xbase + kk * 256 + ((lane * 4) ^ ((kk & 7) << 4))) = o;
        }
    };

    // prologue: Bs chunk0 + gather type0
#pragma unroll
    for (int i = 0; i < 4; ++i) {
        int q = i * 4 + wv;
        GLDS(WK + (size_t)q * 512 + lane * 8, &Bs[0][q * 512]);
    }
    gather(0, 0);
    f32x4 acc[16] = {};
    __syncthreads();    // Bs0 landed (Xs wave-private, covered by program order)

#pragma unroll 1
    for (int c = 0; c < 16; ++c) {
        int cur = c & 1;
        if (c < 15) {
            const __bf16* src = WK + (size_t)(c + 1) * 8192;
#pragma unroll
            for (int i = 0; i < 4; ++i) {
                int q = i * 4 + wv;
                GLDS(src + (size_t)q * 512 + lane * 8, &Bs[cur ^ 1][q * 512]);
            }
        }
        if ((c & 3) == 0 && c < 12) gather((c >> 2) + 1, ((c >> 2) + 1) & 1);
        const char* xw = (const char*)&Xs[(c >> 2) & 1][0] + wv * 4096;
        bf16x8 a = *(const bf16x8*)(xw + lm * 256
                     + ((lq * 16 + (c & 3) * 64) ^ ((lm & 7) << 4)));
#pragma unroll
        for (int nt = 0; nt < 16; ++nt) {
            bf16x8 b = *(const bf16x8*)&Bs[cur][((size_t)lq * 256 + nt * 16 + lm) * 8];
            acc[nt] = __builtin_amdgcn_mfma_f32_16x16x32_bf16(a, b, acc[nt], 0, 0, 0);
        }
        __syncthreads();   // Bs[cur] free for restage; next Bs landed
    }

    // epilogue: relu(acc + degree-weighted bias) -> Acat[:,0:256]
#pragma unroll
    for (int i = 0; i < 4; ++i) {
        int row = wr0 + lq * 4 + i;
        if (row >= NN) continue;
        int ob = row * TT;
        int o0 = offsets[ob], o1 = offsets[ob + 1], o2 = offsets[ob + 2],
            o3 = offsets[ob + 3], o4 = offsets[ob + 4];
        float n0 = (float)(o1 - o0), n1 = (float)(o2 - o1),
              n2 = (float)(o3 - o2), n3 = (float)(o4 - o3);
#pragma unroll
        for (int nt = 0; nt < 16; ++nt) {
            int col = nt * 16 + lm;
            float bias = n0 * b_msg[col] + n1 * b_msg[MM + col]
                       + n2 * b_msg[2 * MM + col] + n3 * b_msg[3 * MM + col];
            Acat[(size_t)row * 384 + col] = (__bf16)fmaxf(acc[nt][i] + bias, 0.f);
        }
    }
}

// ================= fused GRU GEMM: 2x24KB ping-pong halves + reg hold =================
__global__ __launch_bounds__(256, 3)
void gru_gemm(const __bf16* __restrict__ Acat, const __bf16* __restrict__ WBj,
              const float* __restrict__ b512, float* __restrict__ hf,
              __bf16* __restrict__ hbc) {
    __shared__ __bf16 Bs[2][12288];  // 2 x 24 KB ping-pong (total 48 KB, 3 blocks/CU)
    int tid = threadIdx.x, wave = tid >> 6, lane = tid & 63;
    int lm = lane & 15, lq = lane >> 4;
    int r0 = blockIdx.x * 64 + wave * 16;
    int arow = r0 + lm; if (arow >= NN) arow = NN - 1;
    const __bf16* Ap = Acat + (size_t)arow * 384 + lq * 8;

    // stage (j=0, half=0) -> buf0
#pragma unroll
    for (int i = 0; i < 6; ++i) {
        int q = i * 4 + wave;
        GLDS(WBj + (size_t)q * 512 + lane * 8, &Bs[0][q * 512]);
    }

    bf16x8 a[12];
#pragma unroll
    for (int c = 0; c < 12; ++c) a[c] = *(const bf16x8*)(Ap + c * 32);

    __bf16* AcatW = const_cast<__bf16*>(Acat);
    __syncthreads();   // (0,0) landed

#pragma unroll 1
    for (int j = 0; j < 8; ++j) {
        const __bf16* srcj = WBj + (size_t)j * 24576;
        int d = j * 16 + lm;
        int rb = r0 + lq * 4;
        f32x4 ar = {}, az = {}, an = {}, ah = {};

        // ---- phase 2j: stage (j,1)->buf1, prefetch hold, compute half0 from buf0 ----
#pragma unroll
        for (int i = 0; i < 6; ++i) {
            int q = i * 4 + wave;
            GLDS(srcj + 12288 + (size_t)q * 512 + lane * 8, &Bs[1][q * 512]);
        }
        float h0 = hf[(size_t)(rb + 0 < NN ? rb + 0 : NN - 1) * DD + d];
        float h1 = hf[(size_t)(rb + 1 < NN ? rb + 1 : NN - 1) * DD + d];
        float h2 = hf[(size_t)(rb + 2 < NN ? rb + 2 : NN - 1) * DD + d];
        float h3 = hf[(size_t)(rb + 3 < NN ? rb + 3 : NN - 1) * DD + d];
#pragma unroll
        for (int cc = 0; cc < 6; ++cc) {
            const __bf16* Bp = &Bs[0][(cc * 4 + lq) * 512 + lm * 8];
            bf16x8 br = *(const bf16x8*)(Bp);
            bf16x8 bz = *(const bf16x8*)(Bp + 128);
            bf16x8 bn = *(const bf16x8*)(Bp + 256);
            bf16x8 bh = *(const bf16x8*)(Bp + 384);
            ar = __builtin_amdgcn_mfma_f32_16x16x32_bf16(a[cc], br, ar, 0, 0, 0);
            az = __builtin_amdgcn_mfma_f32_16x16x32_bf16(a[cc], bz, az, 0, 0, 0);
            an = __builtin_amdgcn_mfma_f32_16x16x32_bf16(a[cc], bn, an, 0, 0, 0);
            ah = __builtin_amdgcn_mfma_f32_16x16x32_bf16(a[cc], bh, ah, 0, 0, 0);
        }
        __syncthreads();   // (j,1) landed; all waves done with buf0

        // ---- phase 2j+1: stage (j+1,0)->buf0 (if any), compute half1 from buf1 ----
        if (j < 7) {
#pragma unroll
            for (int i = 0; i < 6; ++i) {
                int q = i * 4 + wave;
                GLDS(srcj + 24576 + (size_t)q * 512 + lane * 8, &Bs[0][q * 512]);
            }
        }
#pragma unroll
        for (int cc = 0; cc < 6; ++cc) {
            const __bf16* Bp = &Bs[1][(cc * 4 + lq) * 512 + lm * 8];
            bf16x8 br = *(const bf16x8*)(Bp);
            bf16x8 bz = *(const bf16x8*)(Bp + 128);
            bf16x8 bn = *(const bf16x8*)(Bp + 256);
            bf16x8 bh = *(const bf16x8*)(Bp + 384);
            ar = __builtin_amdgcn_mfma_f32_16x16x32_bf16(a[6 + cc], br, ar, 0, 0, 0);
            az = __builtin_amdgcn_mfma_f32_16x16x32_bf16(a[6 + cc], bz, az, 0, 0, 0);
            an = __builtin_amdgcn_mfma_f32_16x16x32_bf16(a[6 + cc], bn, an, 0, 0, 0);
            ah = __builtin_amdgcn_mfma_f32_16x16x32_bf16(a[6 + cc], bh, ah, 0, 0, 0);
        }
        // ---- epilogue for j (registers + global only; overlaps in-flight stage) ----
        float cbr = b512[d], cbz = b512[128 + d], cbn = b512[256 + d], cbh = b512[384 + d];
        float hv[4] = {h0, h1, h2, h3};
#pragma unroll
        for (int i = 0; i < 4; ++i) {
            int row = rb + i;
            if (row >= NN) continue;
            float pr  = ar[i] + cbr;
            float pz  = az[i] + cbz;
            float pin = an[i] + cbn;
            float phn = ah[i] + cbh;
            float r = fast_sigmoid(pr);
            float z = fast_sigmoid(pz);
            float nv = fast_tanh(pin + r * phn);
            float hnew = (1.f - z) * nv + z * hv[i];
            hf[(size_t)row * DD + d] = hnew;
            __bf16 hb = (__bf16)hnew;
            AcatW[(size_t)row * 384 + 256 + d] = hb;
            hbc[(size_t)row * DD + d] = hb;
        }
        __syncthreads();   // (j+1,0) landed; all waves done with buf1
    }
}

// ================= readout =================
__global__ void attn_kernel(const float* __restrict__ hf, const float* __restrict__ w_gate,
                            const float* __restrict__ b_gate, float* __restrict__ attn) {
    int node = blockIdx.x * 4 + (threadIdx.x >> 6);
    int lane = threadIdx.x & 63;
    if (node >= NN) return;
    size_t base = (size_t)node * DD;
    float s = hf[base + lane * 2] * w_gate[lane * 2]
            + hf[base + lane * 2 + 1] * w_gate[lane * 2 + 1];
    for (int off = 32; off; off >>= 1) s += __shfl_down(s, off);
    if (lane == 0) attn[node] = 1.f / (1.f + expf(-(s + b_gate[0])));
}

__global__ void segsum_kernel(const int* __restrict__ goff, const float* __restrict__ attn,
                              const float* __restrict__ hf, float* __restrict__ sg,
                              float* __restrict__ asumg) {
    int g = blockIdx.x;
    int d = threadIdx.x;
    int beg = goff[g], end = goff[g + 1];
    float s = 0.f, asum = 0.f;
    for (int i = beg; i < end; ++i) {
        float a = attn[i];
        s += a * hf[(size_t)i * DD + d];
        if (d == 0) asum += a;
    }
    sg[g * DD + d] = s;
    if (d == 0) asumg[g] = asum;
}

__global__ void readout_kernel(const float* __restrict__ sg, const float* __restrict__ asumg,
                               const float* __restrict__ W_g, const float* __restrict__ b_g,
                               float* __restrict__ hgraph) {
    int g = blockIdx.x;
    int m = threadIdx.x;
    float acc = asumg[g] * b_g[m];
    for (int d = 0; d < DD; ++d) acc += sg[g * DD + d] * W_g[d * GHID + m];
    hgraph[g * GHID + m] = acc;
}

// ================= launch =================
extern "C" void kernel_launch(void* const* d_in, const int* in_sizes, int n_in,
                              void* d_out, int out_size, void* d_ws, size_t ws_size,
                              hipStream_t stream) {
    const int*   node_types = (const int*)d_in[0];
    const int*   edge_src   = (const int*)d_in[1];
    const int*   edge_dst   = (const int*)d_in[2];
    const int*   edge_type  = (const int*)d_in[3];
    const int*   node2graph = (const int*)d_in[4];
    const float* emb        = (const float*)d_in[5];
    const float* W_msg      = (const float*)d_in[6];
    const float* b_msg      = (const float*)d_in[7];
    const float* W_ih       = (const float*)d_in[8];
    const float* W_hh       = (const float*)d_in[9];
    const float* b_ih       = (const float*)d_in[10];
    const float* b_hh       = (const float*)d_in[11];
    const float* w_gate     = (const float*)d_in[12];
    const float* b_gate     = (const float*)d_in[13];
    const float* W_g        = (const float*)d_in[14];
    const float* b_g        = (const float*)d_in[15];

    float* hf     = (float*)d_out;
    float* hgraph = hf + (size_t)NN * DD;

    char* ws = (char*)d_ws;
    size_t off = 0;
    auto alloc = [&](size_t bytes) -> char* {
        char* p = ws + off;
        off += (bytes + 255) & ~(size_t)255;
        return p;
    };
    __bf16* Acat    = (__bf16*)alloc((size_t)NN * 384 * 2);   // 38.4 MB  [msgs(256)|hb(128)]
    __bf16* hbc     = (__bf16*)alloc((size_t)NN * DD * 2);    // 12.8 MB compact h (gather target)
    __bf16* WK      = (__bf16*)alloc((size_t)16 * 4 * 256 * 8 * 2);
    __bf16* WB      = (__bf16*)alloc((size_t)12 * 4 * 512 * 8 * 2);
    float*  b512    = (float*)alloc(512 * 4);
    float*  attn    = (float*)alloc((size_t)NN * 4);
    float*  sg      = (float*)alloc((size_t)NG * DD * 4);
    float*  asumg   = (float*)alloc((size_t)NG * 4);
    int*    counts  = (int*)alloc((size_t)(NKEY + 1) * 4);
    int*    offsets = (int*)alloc((size_t)(NKEY + 1) * 4);
    int*    cursor  = (int*)alloc((size_t)(NKEY + 1) * 4);
    int*    bsum    = (int*)alloc((size_t)1024 * 4);
    int*    elist   = (int*)alloc((size_t)NE * 4);
    int*    gcounts = (int*)alloc((size_t)(NG + 1) * 4);
    int*    goff    = (int*)alloc((size_t)(NG + 1) * 4);
    int*    gbsum   = (int*)alloc((size_t)8 * 4);

    hipMemsetAsync(counts, 0, (NKEY + 1) * 4, stream);
    hipMemsetAsync(gcounts, 0, (NG + 1) * 4, stream);

    build_WK<<<(16 * 4 * 256 * 8 + 255) / 256, 256, 0, stream>>>(W_msg, WK);
    build_WBj<<<(12 * 4 * 512 * 8 + 255) / 256, 256, 0, stream>>>(W_ih, W_hh, WB);
    build_bias512<<<2, 256, 0, stream>>>(b_ih, b_hh, b512);
    embed_kernel<<<(NN * DD + 255) / 256, 256, 0, stream>>>(node_types, emb, hf, Acat, hbc);

    int nbE = (NKEY + 255) / 256;
    hist_kernel<<<(NE + 255) / 256, 256, 0, stream>>>(edge_src, edge_type, counts);
    scan1<<<nbE, 256, 0, stream>>>(counts, offsets, bsum, NKEY);
    scan2<<<1, 1024, 0, stream>>>(bsum, nbE, offsets, NKEY);
    scan3<<<nbE, 256, 0, stream>>>(offsets, bsum, cursor, NKEY);
    fill_kernel<<<(NE + 255) / 256, 256, 0, stream>>>(edge_src, edge_dst, edge_type, cursor, elist);

    int nbG = (NG + 255) / 256;
    ghist_kernel<<<(NN + 255) / 256, 256, 0, stream>>>(node2graph, gcounts);
    scan1<<<nbG, 256, 0, stream>>>(gcounts, goff, gbsum, NG);
    scan2<<<1, 1024, 0, stream>>>(gbsum, nbG, goff, NG);
    scan3<<<nbG, 256, 0, stream>>>(goff, gbsum, (int*)nullptr, NG);

    int rt = (NN + 63) / 64;  // 782
    for (int p = 0; p < NPASS; ++p) {
        agg_msgs<<<rt, 256, 0, stream>>>(offsets, elist, hbc, WK, b_msg, Acat);
        gru_gemm<<<rt, 256, 0, stream>>>(Acat, WB, b512, hf, hbc);
    }

    attn_kernel<<<(NN + 3) / 4, 256, 0, stream>>>(hf, w_gate, b_gate, attn);
    segsum_kernel<<<NG, 128, 0, stream>>>(goff, attn, hf, sg, asumg);
    readout_kernel<<<NG, GHID, 0, stream>>>(sg, asumg, W_g, b_g, hgraph);
}

// Round 9
// 763.211 us; speedup vs baseline: 1.3734x; 1.3734x over previous
//
#include <hip/hip_runtime.h>
#include <hip/hip_bf16.h>

#define NN 50000
#define NE 800000
#define NG 512
#define DD 128
#define MM 256
#define TT 4
#define NPASS 4
#define GHID 256
#define NKEY (NN * TT)          // CSR keys: src*4 + type

typedef __bf16 bf16x2 __attribute__((ext_vector_type(2)));
typedef __bf16 bf16x4 __attribute__((ext_vector_type(4)));
typedef __bf16 bf16x8 __attribute__((ext_vector_type(8)));
typedef float f32x4 __attribute__((ext_vector_type(4)));

__device__ __forceinline__ float fast_sigmoid(float x) {
    return __builtin_amdgcn_rcpf(1.f + __expf(-x));
}
__device__ __forceinline__ float fast_tanh(float x) {
    float e2 = __expf(2.f * x);
    return 1.f - 2.f * __builtin_amdgcn_rcpf(e2 + 1.f);
}

#define GLDS(SRC, DST) \
    __builtin_amdgcn_global_load_lds( \
        (const __attribute__((address_space(1))) unsigned int*)(SRC), \
        (__attribute__((address_space(3))) unsigned int*)(DST), 16, 0, 0)

// ================= setup: swizzled weights =================
__global__ void build_WK(const float* __restrict__ W_msg, __bf16* __restrict__ WK) {
    int i = blockIdx.x * 256 + threadIdx.x;           // 131072
    if (i >= 16 * 4 * 256 * 8) return;
    int j = i & 7, col = (i >> 3) & 255, g = i >> 11; // g=c*4+lq
    int k = g * 8 + j;
    WK[i] = (__bf16)W_msg[k * 256 + col];
}

// j-major GRU weight layout: WBj[j][c][lq][gate][lm][e]
// value = B[k=(c*4+lq)*8+e][col = gate*128 + j*16 + lm]
__global__ void build_WBj(const float* __restrict__ W_ih, const float* __restrict__ W_hh,
                          __bf16* __restrict__ WB) {
    int i = blockIdx.x * 256 + threadIdx.x;           // 196608
    if (i >= 8 * 12 * 4 * 4 * 16 * 8) return;
    int low = i & 127;
    int lm = low >> 3, e = low & 7;
    int rest = i >> 7;
    int g  = rest & 3;
    int lq = (rest >> 2) & 3;
    int jc = rest >> 4;          // j*12 + c
    int c  = jc % 12;
    int j  = jc / 12;
    int k   = (c * 4 + lq) * 8 + e;     // 0..383
    int col = g * 128 + j * 16 + lm;    // 0..511
    float v = 0.f;
    if (col < 256) {
        v = (k < 256) ? W_ih[col * 256 + k] : W_hh[col * 128 + (k - 256)];
    } else if (col < 384) {
        if (k < 256) v = W_ih[col * 256 + k];
    } else {
        if (k >= 256) v = W_hh[(col - 128) * 128 + (k - 256)];
    }
    WB[i] = (__bf16)v;
}

__global__ void build_bias512(const float* __restrict__ b_ih, const float* __restrict__ b_hh,
                              float* __restrict__ b512) {
    int c = blockIdx.x * 256 + threadIdx.x;
    if (c >= 512) return;
    float v;
    if (c < 256) v = b_ih[c] + b_hh[c];
    else if (c < 384) v = b_ih[c];
    else v = b_hh[c - 128];
    b512[c] = v;
}

// ================= embedding =================
__global__ void embed_kernel(const int* __restrict__ node_types,
                             const float* __restrict__ emb,
                             float* __restrict__ hf, __bf16* __restrict__ Acat,
                             __bf16* __restrict__ hbc) {
    int t = blockIdx.x * 256 + threadIdx.x;
    if (t >= NN * DD) return;
    int node = t >> 7, d = t & 127;
    float v = emb[node_types[node] * DD + d];
    hf[t] = v;
    __bf16 b = (__bf16)v;
    Acat[(size_t)node * 384 + 256 + d] = b;
    hbc[t] = b;
}

// ================= CSR build (keyed by src*4+type) =================
__global__ void hist_kernel(const int* __restrict__ src, const int* __restrict__ et,
                            int* __restrict__ counts) {
    int e = blockIdx.x * 256 + threadIdx.x;
    if (e < NE) atomicAdd(&counts[src[e] * TT + et[e]], 1);
}

__global__ void ghist_kernel(const int* __restrict__ n2g, int* __restrict__ gcounts) {
    int i = blockIdx.x * 256 + threadIdx.x;
    if (i < NN) atomicAdd(&gcounts[n2g[i]], 1);
}

__global__ void scan1(const int* __restrict__ counts, int* __restrict__ offsets,
                      int* __restrict__ bsum, int n) {
    __shared__ int sm[256];
    int i = blockIdx.x * 256 + threadIdx.x;
    int v = (i < n) ? counts[i] : 0;
    sm[threadIdx.x] = v;
    __syncthreads();
    for (int off = 1; off < 256; off <<= 1) {
        int t = (threadIdx.x >= off) ? sm[threadIdx.x - off] : 0;
        __syncthreads();
        sm[threadIdx.x] += t;
        __syncthreads();
    }
    if (i < n) offsets[i] = sm[threadIdx.x] - v;
    if (threadIdx.x == 255) bsum[blockIdx.x] = sm[255];
}

__global__ void scan2(int* __restrict__ bsum, int nb, int* __restrict__ offsets, int n) {
    __shared__ int sm[1024];
    int v = (threadIdx.x < nb) ? bsum[threadIdx.x] : 0;
    sm[threadIdx.x] = v;
    __syncthreads();
    for (int off = 1; off < 1024; off <<= 1) {
        int t = (threadIdx.x >= off) ? sm[threadIdx.x - off] : 0;
        __syncthreads();
        sm[threadIdx.x] += t;
        __syncthreads();
    }
    if (threadIdx.x < nb) bsum[threadIdx.x] = sm[threadIdx.x] - v;
    if (threadIdx.x == 1023) offsets[n] = sm[1023];
}

__global__ void scan3(int* __restrict__ offsets, const int* __restrict__ bsum,
                      int* __restrict__ cursor, int n) {
    int i = blockIdx.x * 256 + threadIdx.x;
    if (i < n) {
        int o = offsets[i] + bsum[blockIdx.x];
        offsets[i] = o;
        if (cursor) cursor[i] = o;
    }
}

__global__ void fill_kernel(const int* __restrict__ src, const int* __restrict__ dst,
                            const int* __restrict__ et, int* __restrict__ cursor,
                            int* __restrict__ elist) {
    int e = blockIdx.x * 256 + threadIdx.x;
    if (e >= NE) return;
    int pos = atomicAdd(&cursor[src[e] * TT + et[e]], 1);
    elist[pos] = dst[e];
}

// ================= aggregation: wave per SRC ROW (all 4 types), branchless batch-0 =====
// One wave = one row: 4 keys, up to 32 gathers in flight, one dependency chain.
// Indices via clamped scalar loads; invalid slots masked by uniform 0/1 FMA.
__global__ void agg4(const int* __restrict__ offsets, const int* __restrict__ elist,
                     const __bf16* __restrict__ hbc, __bf16* __restrict__ X) {
    int row = blockIdx.x * 4 + (threadIdx.x >> 6);
    if (row >= NN) return;
    int lane = threadIdx.x & 63;
    const __bf16* hb = hbc + lane * 2;
    int ob = row * TT;
    int o0 = __builtin_amdgcn_readfirstlane(offsets[ob]);
    int o1 = __builtin_amdgcn_readfirstlane(offsets[ob + 1]);
    int o2 = __builtin_amdgcn_readfirstlane(offsets[ob + 2]);
    int o3 = __builtin_amdgcn_readfirstlane(offsets[ob + 3]);
    int o4 = __builtin_amdgcn_readfirstlane(offsets[ob + 4]);
    int begs[4] = {o0, o1, o2, o3};
    int ends[4] = {o1, o2, o3, o4};

    float ax[4] = {0.f, 0.f, 0.f, 0.f};
    float ay[4] = {0.f, 0.f, 0.f, 0.f};

    // ---- batch 0: 8 clamped gathers x 4 types, ALL issued before any accumulate ----
    bf16x2 v[4][8];
    int nb[4];
#pragma unroll
    for (int t = 0; t < 4; ++t) {
        int beg = begs[t], end = ends[t];
        nb[t] = end - beg;
        int e1 = end - 1;
        if (e1 < 0) e1 = 0;                     // empty first key
        int idx[8];
#pragma unroll
        for (int k = 0; k < 8; ++k) {
            int p = beg + k; if (p > e1) p = e1;   // clamp: dup line, L1-hit
            idx[k] = elist[p];                      // uniform -> s_load
        }
#pragma unroll
        for (int k = 0; k < 8; ++k)
            v[t][k] = *(const bf16x2*)(hb + (size_t)idx[k] * DD);  // saddr gather
    }
#pragma unroll
    for (int t = 0; t < 4; ++t) {
#pragma unroll
        for (int k = 0; k < 8; ++k) {
            float m = (nb[t] > k) ? 1.f : 0.f;     // uniform mask
            ax[t] += m * (float)v[t][k].x;
            ay[t] += m * (float)v[t][k].y;
        }
    }

    // ---- tails (deg > 8 per type, rare): same masked 8-block in a loop ----
#pragma unroll
    for (int t = 0; t < 4; ++t) {
        int end = ends[t];
        for (int base = begs[t] + 8; base < end; base += 8) {
            int nb2 = end - base; if (nb2 > 8) nb2 = 8;
            int e1 = end - 1;
            int idx[8];
#pragma unroll
            for (int k = 0; k < 8; ++k) {
                int p = base + k; if (p > e1) p = e1;
                idx[k] = elist[p];
            }
            bf16x2 tv[8];
#pragma unroll
            for (int k = 0; k < 8; ++k)
                tv[k] = *(const bf16x2*)(hb + (size_t)idx[k] * DD);
#pragma unroll
            for (int k = 0; k < 8; ++k) {
                float m = (nb2 > k) ? 1.f : 0.f;
                ax[t] += m * (float)tv[k].x;
                ay[t] += m * (float)tv[k].y;
            }
        }
    }

    // ---- store: 4 consecutive X rows (= X[row][512] for the GEMM) ----
#pragma unroll
    for (int t = 0; t < 4; ++t) {
        bf16x2 o;
        o.x = (__bf16)ax[t];
        o.y = (__bf16)ay[t];
        *(bf16x2*)(X + (size_t)(ob + t) * 128 + lane * 2) = o;
    }
}

// ================= msgs GEMM: 2-phase ping-pong, global_load_lds staging =================
__global__ void msgs_gemm2(const __bf16* __restrict__ X, const __bf16* __restrict__ WK,
                           const float* __restrict__ b_msg, const int* __restrict__ offsets,
                           __bf16* __restrict__ Acat) {
    __shared__ __bf16 Bs[2][8192];   // 2 x 16 KB ping-pong
    int tid = threadIdx.x, wave = tid >> 6, lane = tid & 63;
    int lm = lane & 15, lq = lane >> 4;
    int r0 = blockIdx.x * 64 + wave * 16;
    int arow = r0 + lm; if (arow >= NN) arow = NN - 1;
    const __bf16* Ap = X + (size_t)arow * 512 + lq * 8;

    // stage c=0 -> buf0
#pragma unroll
    for (int i = 0; i < 4; ++i) {
        int q = i * 4 + wave;
        GLDS(WK + (size_t)q * 512 + lane * 8, &Bs[0][q * 512]);
    }
    bf16x8 acur = *(const bf16x8*)(Ap);
    f32x4 acc[16] = {};
    __syncthreads();    // stage 0 landed

#pragma unroll 1
    for (int c = 0; c < 16; ++c) {
        int cur = c & 1;
        bf16x8 anext = acur;
        if (c < 15) {
            const __bf16* src = WK + (size_t)(c + 1) * 8192;
#pragma unroll
            for (int i = 0; i < 4; ++i) {
                int q = i * 4 + wave;
                GLDS(src + (size_t)q * 512 + lane * 8, &Bs[cur ^ 1][q * 512]);
            }
            anext = *(const bf16x8*)(Ap + (c + 1) * 32);
        }
#pragma unroll
        for (int nt = 0; nt < 16; ++nt) {
            bf16x8 b = *(const bf16x8*)&Bs[cur][((size_t)lq * 256 + nt * 16 + lm) * 8];
            acc[nt] = __builtin_amdgcn_mfma_f32_16x16x32_bf16(acur, b, acc[nt], 0, 0, 0);
        }
        __syncthreads();   // drains next stage + all waves done reading Bs[cur]
        acur = anext;
    }
#pragma unroll
    for (int i = 0; i < 4; ++i) {
        int row = r0 + lq * 4 + i;
        if (row >= NN) continue;
        int ob = row * TT;
        int o0 = offsets[ob], o1 = offsets[ob + 1], o2 = offsets[ob + 2],
            o3 = offsets[ob + 3], o4 = offsets[ob + 4];
        float n0 = (float)(o1 - o0), n1 = (float)(o2 - o1),
              n2 = (float)(o3 - o2), n3 = (float)(o4 - o3);
#pragma unroll
        for (int nt = 0; nt < 16; ++nt) {
            int col = nt * 16 + lm;
            float bias = n0 * b_msg[col] + n1 * b_msg[MM + col]
                       + n2 * b_msg[2 * MM + col] + n3 * b_msg[3 * MM + col];
            Acat[(size_t)row * 384 + col] = (__bf16)fmaxf(acc[nt][i] + bias, 0.f);
        }
    }
}

// ================= fused GRU GEMM: 2x24KB ping-pong halves + reg hold =================
__global__ __launch_bounds__(256, 3)
void gru_gemm(const __bf16* __restrict__ Acat, const __bf16* __restrict__ WBj,
              const float* __restrict__ b512, float* __restrict__ hf,
              __bf16* __restrict__ hbc) {
    __shared__ __bf16 Bs[2][12288];  // 2 x 24 KB ping-pong (total 48 KB, 3 blocks/CU)
    int tid = threadIdx.x, wave = tid >> 6, lane = tid & 63;
    int lm = lane & 15, lq = lane >> 4;
    int r0 = blockIdx.x * 64 + wave * 16;
    int arow = r0 + lm; if (arow >= NN) arow = NN - 1;
    const __bf16* Ap = Acat + (size_t)arow * 384 + lq * 8;

    // stage (j=0, half=0) -> buf0
#pragma unroll
    for (int i = 0; i < 6; ++i) {
        int q = i * 4 + wave;
        GLDS(WBj + (size_t)q * 512 + lane * 8, &Bs[0][q * 512]);
    }

    bf16x8 a[12];
#pragma unroll
    for (int c = 0; c < 12; ++c) a[c] = *(const bf16x8*)(Ap + c * 32);

    __bf16* AcatW = const_cast<__bf16*>(Acat);
    __syncthreads();   // (0,0) landed

#pragma unroll 1
    for (int j = 0; j < 8; ++j) {
        const __bf16* srcj = WBj + (size_t)j * 24576;
        int d = j * 16 + lm;
        int rb = r0 + lq * 4;
        f32x4 ar = {}, az = {}, an = {}, ah = {};

        // ---- phase 2j: stage (j,1)->buf1, prefetch hold, compute half0 from buf0 ----
#pragma unroll
        for (int i = 0; i < 6; ++i) {
            int q = i * 4 + wave;
            GLDS(srcj + 12288 + (size_t)q * 512 + lane * 8, &Bs[1][q * 512]);
        }
        float h0 = hf[(size_t)(rb + 0 < NN ? rb + 0 : NN - 1) * DD + d];
        float h1 = hf[(size_t)(rb + 1 < NN ? rb + 1 : NN - 1) * DD + d];
        float h2 = hf[(size_t)(rb + 2 < NN ? rb + 2 : NN - 1) * DD + d];
        float h3 = hf[(size_t)(rb + 3 < NN ? rb + 3 : NN - 1) * DD + d];
#pragma unroll
        for (int cc = 0; cc < 6; ++cc) {
            const __bf16* Bp = &Bs[0][(cc * 4 + lq) * 512 + lm * 8];
            bf16x8 br = *(const bf16x8*)(Bp);
            bf16x8 bz = *(const bf16x8*)(Bp + 128);
            bf16x8 bn = *(const bf16x8*)(Bp + 256);
            bf16x8 bh = *(const bf16x8*)(Bp + 384);
            ar = __builtin_amdgcn_mfma_f32_16x16x32_bf16(a[cc], br, ar, 0, 0, 0);
            az = __builtin_amdgcn_mfma_f32_16x16x32_bf16(a[cc], bz, az, 0, 0, 0);
            an = __builtin_amdgcn_mfma_f32_16x16x32_bf16(a[cc], bn, an, 0, 0, 0);
            ah = __builtin_amdgcn_mfma_f32_16x16x32_bf16(a[cc], bh, ah, 0, 0, 0);
        }
        __syncthreads();   // (j,1) landed; all waves done with buf0

        // ---- phase 2j+1: stage (j+1,0)->buf0 (if any), compute half1 from buf1 ----
        if (j < 7) {
#pragma unroll
            for (int i = 0; i < 6; ++i) {
                int q = i * 4 + wave;
                GLDS(srcj + 24576 + (size_t)q * 512 + lane * 8, &Bs[0][q * 512]);
            }
        }
#pragma unroll
        for (int cc = 0; cc < 6; ++cc) {
            const __bf16* Bp = &Bs[1][(cc * 4 + lq) * 512 + lm * 8];
            bf16x8 br = *(const bf16x8*)(Bp);
            bf16x8 bz = *(const bf16x8*)(Bp + 128);
            bf16x8 bn = *(const bf16x8*)(Bp + 256);
            bf16x8 bh = *(const bf16x8*)(Bp + 384);
            ar = __builtin_amdgcn_mfma_f32_16x16x32_bf16(a[6 + cc], br, ar, 0, 0, 0);
            az = __builtin_amdgcn_mfma_f32_16x16x32_bf16(a[6 + cc], bz, az, 0, 0, 0);
            an = __builtin_amdgcn_mfma_f32_16x16x32_bf16(a[6 + cc], bn, an, 0, 0, 0);
            ah = __builtin_amdgcn_mfma_f32_16x16x32_bf16(a[6 + cc], bh, ah, 0, 0, 0);
        }
        // ---- epilogue for j (registers + global only; overlaps in-flight stage) ----
        float cbr = b512[d], cbz = b512[128 + d], cbn = b512[256 + d], cbh = b512[384 + d];
        float hv[4] = {h0, h1, h2, h3};
#pragma unroll
        for (int i = 0; i < 4; ++i) {
            int row = rb + i;
            if (row >= NN) continue;
            float pr  = ar[i] + cbr;
            float pz  = az[i] + cbz;
            float pin = an[i] + cbn;
            float phn = ah[i] + cbh;
            float r = fast_sigmoid(pr);
            float z = fast_sigmoid(pz);
            float nv = fast_tanh(pin + r * phn);
            float hnew = (1.f - z) * nv + z * hv[i];
            hf[(size_t)row * DD + d] = hnew;
            __bf16 hb = (__bf16)hnew;
            AcatW[(size_t)row * 384 + 256 + d] = hb;
            hbc[(size_t)row * DD + d] = hb;
        }
        __syncthreads();   // (j+1,0) landed; all waves done with buf1
    }
}

// ================= readout =================
__global__ void attn_kernel(const float* __restrict__ hf, const float* __restrict__ w_gate,
                            const float* __restrict__ b_gate, float* __restrict__ attn) {
    int node = blockIdx.x * 4 + (threadIdx.x >> 6);
    int lane = threadIdx.x & 63;
    if (node >= NN) return;
    size_t base = (size_t)node * DD;
    float s = hf[base + lane * 2] * w_gate[lane * 2]
            + hf[base + lane * 2 + 1] * w_gate[lane * 2 + 1];
    for (int off = 32; off; off >>= 1) s += __shfl_down(s, off);
    if (lane == 0) attn[node] = 1.f / (1.f + expf(-(s + b_gate[0])));
}

__global__ void segsum_kernel(const int* __restrict__ goff, const float* __restrict__ attn,
                              const float* __restrict__ hf, float* __restrict__ sg,
                              float* __restrict__ asumg) {
    int g = blockIdx.x;
    int d = threadIdx.x;
    int beg = goff[g], end = goff[g + 1];
    float s = 0.f, asum = 0.f;
    for (int i = beg; i < end; ++i) {
        float a = attn[i];
        s += a * hf[(size_t)i * DD + d];
        if (d == 0) asum += a;
    }
    sg[g * DD + d] = s;
    if (d == 0) asumg[g] = asum;
}

__global__ void readout_kernel(const float* __restrict__ sg, const float* __restrict__ asumg,
                               const float* __restrict__ W_g, const float* __restrict__ b_g,
                               float* __restrict__ hgraph) {
    int g = blockIdx.x;
    int m = threadIdx.x;
    float acc = asumg[g] * b_g[m];
    for (int d = 0; d < DD; ++d) acc += sg[g * DD + d] * W_g[d * GHID + m];
    hgraph[g * GHID + m] = acc;
}

// ================= launch =================
extern "C" void kernel_launch(void* const* d_in, const int* in_sizes, int n_in,
                              void* d_out, int out_size, void* d_ws, size_t ws_size,
                              hipStream_t stream) {
    const int*   node_types = (const int*)d_in[0];
    const int*   edge_src   = (const int*)d_in[1];
    const int*   edge_dst   = (const int*)d_in[2];
    const int*   edge_type  = (const int*)d_in[3];
    const int*   node2graph = (const int*)d_in[4];
    const float* emb        = (const float*)d_in[5];
    const float* W_msg      = (const float*)d_in[6];
    const float* b_msg      = (const float*)d_in[7];
    const float* W_ih       = (const float*)d_in[8];
    const float* W_hh       = (const float*)d_in[9];
    const float* b_ih       = (const float*)d_in[10];
    const float* b_hh       = (const float*)d_in[11];
    const float* w_gate     = (const float*)d_in[12];
    const float* b_gate     = (const float*)d_in[13];
    const float* W_g        = (const float*)d_in[14];
    const float* b_g        = (const float*)d_in[15];

    float* hf     = (float*)d_out;
    float* hgraph = hf + (size_t)NN * DD;

    char* ws = (char*)d_ws;
    size_t off = 0;
    auto alloc = [&](size_t bytes) -> char* {
        char* p = ws + off;
        off += (bytes + 255) & ~(size_t)255;
        return p;
    };
    __bf16* X       = (__bf16*)alloc((size_t)NN * 512 * 2);   // 51.2 MB
    __bf16* Acat    = (__bf16*)alloc((size_t)NN * 384 * 2);   // 38.4 MB  [msgs(256)|hb(128)]
    __bf16* hbc     = (__bf16*)alloc((size_t)NN * DD * 2);    // 12.8 MB compact h (gather target)
    __bf16* WK      = (__bf16*)alloc((size_t)16 * 4 * 256 * 8 * 2);
    __bf16* WB      = (__bf16*)alloc((size_t)12 * 4 * 512 * 8 * 2);
    float*  b512    = (float*)alloc(512 * 4);
    float*  attn    = (float*)alloc((size_t)NN * 4);
    float*  sg      = (float*)alloc((size_t)NG * DD * 4);
    float*  asumg   = (float*)alloc((size_t)NG * 4);
    int*    counts  = (int*)alloc((size_t)(NKEY + 1) * 4);
    int*    offsets = (int*)alloc((size_t)(NKEY + 1) * 4);
    int*    cursor  = (int*)alloc((size_t)(NKEY + 1) * 4);
    int*    bsum    = (int*)alloc((size_t)1024 * 4);
    int*    elist   = (int*)alloc((size_t)NE * 4);
    int*    gcounts = (int*)alloc((size_t)(NG + 1) * 4);
    int*    goff    = (int*)alloc((size_t)(NG + 1) * 4);
    int*    gbsum   = (int*)alloc((size_t)8 * 4);

    hipMemsetAsync(counts, 0, (NKEY + 1) * 4, stream);
    hipMemsetAsync(gcounts, 0, (NG + 1) * 4, stream);

    build_WK<<<(16 * 4 * 256 * 8 + 255) / 256, 256, 0, stream>>>(W_msg, WK);
    build_WBj<<<(12 * 4 * 512 * 8 + 255) / 256, 256, 0, stream>>>(W_ih, W_hh, WB);
    build_bias512<<<2, 256, 0, stream>>>(b_ih, b_hh, b512);
    embed_kernel<<<(NN * DD + 255) / 256, 256, 0, stream>>>(node_types, emb, hf, Acat, hbc);

    int nbE = (NKEY + 255) / 256;
    hist_kernel<<<(NE + 255) / 256, 256, 0, stream>>>(edge_src, edge_type, counts);
    scan1<<<nbE, 256, 0, stream>>>(counts, offsets, bsum, NKEY);
    scan2<<<1, 1024, 0, stream>>>(bsum, nbE, offsets, NKEY);
    scan3<<<nbE, 256, 0, stream>>>(offsets, bsum, cursor, NKEY);
    fill_kernel<<<(NE + 255) / 256, 256, 0, stream>>>(edge_src, edge_dst, edge_type, cursor, elist);

    int nbG = (NG + 255) / 256;
    ghist_kernel<<<(NN + 255) / 256, 256, 0, stream>>>(node2graph, gcounts);
    scan1<<<nbG, 256, 0, stream>>>(gcounts, goff, gbsum, NG);
    scan2<<<1, 1024, 0, stream>>>(gbsum, nbG, goff, NG);
    scan3<<<nbG, 256, 0, stream>>>(goff, gbsum, (int*)nullptr, NG);

    int rt = (NN + 63) / 64;  // 782
    for (int p = 0; p < NPASS; ++p) {
        agg4<<<(NN + 3) / 4, 256, 0, stream>>>(offsets, elist, hbc, X);
        msgs_gemm2<<<rt, 256, 0, stream>>>(X, WK, b_msg, offsets, Acat);
        gru_gemm<<<rt, 256, 0, stream>>>(Acat, WB, b512, hf, hbc);
    }

    attn_kernel<<<(NN + 3) / 4, 256, 0, stream>>>(hf, w_gate, b_gate, attn);
    segsum_kernel<<<NG, 128, 0, stream>>>(goff, attn, hf, sg, asumg);
    readout_kernel<<<NG, GHID, 0, stream>>>(sg, asumg, W_g, b_g, hgraph);
}

// Round 10
// 757.211 us; speedup vs baseline: 1.3843x; 1.0079x over previous
//
#include <hip/hip_runtime.h>
#include <hip/hip_bf16.h>

#define NN 50000
#define NE 800000
#define NG 512
#define DD 128
#define MM 256
#define TT 4
#define NPASS 4
#define GHID 256
#define NKEY (NN * TT)          // CSR keys: src*4 + type

typedef __bf16 bf16x2 __attribute__((ext_vector_type(2)));
typedef __bf16 bf16x4 __attribute__((ext_vector_type(4)));
typedef __bf16 bf16x8 __attribute__((ext_vector_type(8)));
typedef float f32x4 __attribute__((ext_vector_type(4)));

__device__ __forceinline__ float fast_sigmoid(float x) {
    return __builtin_amdgcn_rcpf(1.f + __expf(-x));
}
__device__ __forceinline__ float fast_tanh(float x) {
    float e2 = __expf(2.f * x);
    return 1.f - 2.f * __builtin_amdgcn_rcpf(e2 + 1.f);
}

#define GLDS(SRC, DST) \
    __builtin_amdgcn_global_load_lds( \
        (const __attribute__((address_space(1))) unsigned int*)(SRC), \
        (__attribute__((address_space(3))) unsigned int*)(DST), 16, 0, 0)

// ================= setup: swizzled weights =================
__global__ void build_WK(const float* __restrict__ W_msg, __bf16* __restrict__ WK) {
    int i = blockIdx.x * 256 + threadIdx.x;           // 131072
    if (i >= 16 * 4 * 256 * 8) return;
    int j = i & 7, col = (i >> 3) & 255, g = i >> 11; // g=c*4+lq
    int k = g * 8 + j;
    WK[i] = (__bf16)W_msg[k * 256 + col];
}

// j-major GRU weight layout: WBj[j][c][lq][gate][lm][e]
// value = B[k=(c*4+lq)*8+e][col = gate*128 + j*16 + lm]
__global__ void build_WBj(const float* __restrict__ W_ih, const float* __restrict__ W_hh,
                          __bf16* __restrict__ WB) {
    int i = blockIdx.x * 256 + threadIdx.x;           // 196608
    if (i >= 8 * 12 * 4 * 4 * 16 * 8) return;
    int low = i & 127;
    int lm = low >> 3, e = low & 7;
    int rest = i >> 7;
    int g  = rest & 3;
    int lq = (rest >> 2) & 3;
    int jc = rest >> 4;          // j*12 + c
    int c  = jc % 12;
    int j  = jc / 12;
    int k   = (c * 4 + lq) * 8 + e;     // 0..383
    int col = g * 128 + j * 16 + lm;    // 0..511
    float v = 0.f;
    if (col < 256) {
        v = (k < 256) ? W_ih[col * 256 + k] : W_hh[col * 128 + (k - 256)];
    } else if (col < 384) {
        if (k < 256) v = W_ih[col * 256 + k];
    } else {
        if (k >= 256) v = W_hh[(col - 128) * 128 + (k - 256)];
    }
    WB[i] = (__bf16)v;
}

__global__ void build_bias512(const float* __restrict__ b_ih, const float* __restrict__ b_hh,
                              float* __restrict__ b512) {
    int c = blockIdx.x * 256 + threadIdx.x;
    if (c >= 512) return;
    float v;
    if (c < 256) v = b_ih[c] + b_hh[c];
    else if (c < 384) v = b_ih[c];
    else v = b_hh[c - 128];
    b512[c] = v;
}

// ================= embedding =================
__global__ void embed_kernel(const int* __restrict__ node_types,
                             const float* __restrict__ emb,
                             float* __restrict__ hf, __bf16* __restrict__ hbc) {
    int t = blockIdx.x * 256 + threadIdx.x;
    if (t >= NN * DD) return;
    int node = t >> 7;
    float v = emb[node_types[node] * DD + (t & 127)];
    hf[t] = v;
    hbc[t] = (__bf16)v;
}

// ================= CSR build (keyed by src*4+type) =================
__global__ void hist_kernel(const int* __restrict__ src, const int* __restrict__ et,
                            int* __restrict__ counts) {
    int e = blockIdx.x * 256 + threadIdx.x;
    if (e < NE) atomicAdd(&counts[src[e] * TT + et[e]], 1);
}

__global__ void ghist_kernel(const int* __restrict__ n2g, int* __restrict__ gcounts) {
    int i = blockIdx.x * 256 + threadIdx.x;
    if (i < NN) atomicAdd(&gcounts[n2g[i]], 1);
}

__global__ void scan1(const int* __restrict__ counts, int* __restrict__ offsets,
                      int* __restrict__ bsum, int n) {
    __shared__ int sm[256];
    int i = blockIdx.x * 256 + threadIdx.x;
    int v = (i < n) ? counts[i] : 0;
    sm[threadIdx.x] = v;
    __syncthreads();
    for (int off = 1; off < 256; off <<= 1) {
        int t = (threadIdx.x >= off) ? sm[threadIdx.x - off] : 0;
        __syncthreads();
        sm[threadIdx.x] += t;
        __syncthreads();
    }
    if (i < n) offsets[i] = sm[threadIdx.x] - v;
    if (threadIdx.x == 255) bsum[blockIdx.x] = sm[255];
}

__global__ void scan2(int* __restrict__ bsum, int nb, int* __restrict__ offsets, int n) {
    __shared__ int sm[1024];
    int v = (threadIdx.x < nb) ? bsum[threadIdx.x] : 0;
    sm[threadIdx.x] = v;
    __syncthreads();
    for (int off = 1; off < 1024; off <<= 1) {
        int t = (threadIdx.x >= off) ? sm[threadIdx.x - off] : 0;
        __syncthreads();
        sm[threadIdx.x] += t;
        __syncthreads();
    }
    if (threadIdx.x < nb) bsum[threadIdx.x] = sm[threadIdx.x] - v;
    if (threadIdx.x == 1023) offsets[n] = sm[1023];
}

__global__ void scan3(int* __restrict__ offsets, const int* __restrict__ bsum,
                      int* __restrict__ cursor, int n) {
    int i = blockIdx.x * 256 + threadIdx.x;
    if (i < n) {
        int o = offsets[i] + bsum[blockIdx.x];
        offsets[i] = o;
        if (cursor) cursor[i] = o;
    }
}

__global__ void fill_kernel(const int* __restrict__ src, const int* __restrict__ dst,
                            const int* __restrict__ et, int* __restrict__ cursor,
                            int* __restrict__ elist) {
    int e = blockIdx.x * 256 + threadIdx.x;
    if (e >= NE) return;
    int pos = atomicAdd(&cursor[src[e] * TT + et[e]], 1);
    elist[pos] = dst[e];
}

// ================= aggregation: wave per SRC ROW (all 4 types), branchless batch-0 =====
__global__ void agg4(const int* __restrict__ offsets, const int* __restrict__ elist,
                     const __bf16* __restrict__ hbc, __bf16* __restrict__ X) {
    int row = blockIdx.x * 4 + (threadIdx.x >> 6);
    if (row >= NN) return;
    int lane = threadIdx.x & 63;
    const __bf16* hb = hbc + lane * 2;
    int ob = row * TT;
    int o0 = __builtin_amdgcn_readfirstlane(offsets[ob]);
    int o1 = __builtin_amdgcn_readfirstlane(offsets[ob + 1]);
    int o2 = __builtin_amdgcn_readfirstlane(offsets[ob + 2]);
    int o3 = __builtin_amdgcn_readfirstlane(offsets[ob + 3]);
    int o4 = __builtin_amdgcn_readfirstlane(offsets[ob + 4]);
    int begs[4] = {o0, o1, o2, o3};
    int ends[4] = {o1, o2, o3, o4};

    float ax[4] = {0.f, 0.f, 0.f, 0.f};
    float ay[4] = {0.f, 0.f, 0.f, 0.f};

    // ---- batch 0: 8 clamped gathers x 4 types, ALL issued before any accumulate ----
    bf16x2 v[4][8];
    int nb[4];
#pragma unroll
    for (int t = 0; t < 4; ++t) {
        int beg = begs[t], end = ends[t];
        nb[t] = end - beg;
        int e1 = end - 1;
        if (e1 < 0) e1 = 0;
        int idx[8];
#pragma unroll
        for (int k = 0; k < 8; ++k) {
            int p = beg + k; if (p > e1) p = e1;
            idx[k] = elist[p];
        }
#pragma unroll
        for (int k = 0; k < 8; ++k)
            v[t][k] = *(const bf16x2*)(hb + (size_t)idx[k] * DD);
    }
#pragma unroll
    for (int t = 0; t < 4; ++t) {
#pragma unroll
        for (int k = 0; k < 8; ++k) {
            float m = (nb[t] > k) ? 1.f : 0.f;
            ax[t] += m * (float)v[t][k].x;
            ay[t] += m * (float)v[t][k].y;
        }
    }

    // ---- tails (deg > 8 per type, rare) ----
#pragma unroll
    for (int t = 0; t < 4; ++t) {
        int end = ends[t];
        for (int base = begs[t] + 8; base < end; base += 8) {
            int nb2 = end - base; if (nb2 > 8) nb2 = 8;
            int e1 = end - 1;
            int idx[8];
#pragma unroll
            for (int k = 0; k < 8; ++k) {
                int p = base + k; if (p > e1) p = e1;
                idx[k] = elist[p];
            }
            bf16x2 tv[8];
#pragma unroll
            for (int k = 0; k < 8; ++k)
                tv[k] = *(const bf16x2*)(hb + (size_t)idx[k] * DD);
#pragma unroll
            for (int k = 0; k < 8; ++k) {
                float m = (nb2 > k) ? 1.f : 0.f;
                ax[t] += m * (float)tv[k].x;
                ay[t] += m * (float)tv[k].y;
            }
        }
    }

#pragma unroll
    for (int t = 0; t < 4; ++t) {
        bf16x2 o;
        o.x = (__bf16)ax[t];
        o.y = (__bf16)ay[t];
        *(bf16x2*)(X + (size_t)(ob + t) * 128 + lane * 2) = o;
    }
}

// ================= FUSED msgs GEMM + GRU GEMM =================
// Phase A = msgs_gemm2 loop, epilogue -> wave-private swizzled LDS slab Xl.
// Phase B = gru_gemm loop; A-frags: msgs from Xl (ds_read), h from hbc.
// Same wave owns the same 16 rows in both phases -> Xl needs no barrier.
__global__ __launch_bounds__(256, 2)
void msgs_gru(const __bf16* __restrict__ X, const __bf16* __restrict__ WK,
              const float* __restrict__ b_msg, const int* __restrict__ offsets,
              const __bf16* __restrict__ WBj, const float* __restrict__ b512,
              float* __restrict__ hf, __bf16* __restrict__ hbc) {
    __shared__ __bf16 Bs[2][12288];   // 48 KB (phase A uses first 16 KB of each half)
    __shared__ __bf16 Xl[16384];      // 32 KB: wave slab 16 rows x 256 cols, swizzled
    int tid = threadIdx.x, wave = tid >> 6, lane = tid & 63;
    int lm = lane & 15, lq = lane >> 4;
    int r0 = blockIdx.x * 64 + wave * 16;
    int arow = r0 + lm; if (arow >= NN) arow = NN - 1;
    char* xlw = (char*)&Xl[0] + wave * 8192;

    // ---------------- phase A: msgs = relu(X @ WK + deg-bias) ----------------
    {
        const __bf16* Ap = X + (size_t)arow * 512 + lq * 8;
#pragma unroll
        for (int i = 0; i < 4; ++i) {
            int q = i * 4 + wave;
            GLDS(WK + (size_t)q * 512 + lane * 8, &Bs[0][q * 512]);
        }
        bf16x8 acur = *(const bf16x8*)(Ap);
        f32x4 acc[16] = {};
        __syncthreads();    // stage 0 landed

#pragma unroll 1
        for (int c = 0; c < 16; ++c) {
            int cur = c & 1;
            bf16x8 anext = acur;
            if (c < 15) {
                const __bf16* src = WK + (size_t)(c + 1) * 8192;
#pragma unroll
                for (int i = 0; i < 4; ++i) {
                    int q = i * 4 + wave;
                    GLDS(src + (size_t)q * 512 + lane * 8, &Bs[cur ^ 1][q * 512]);
                }
                anext = *(const bf16x8*)(Ap + (c + 1) * 32);
            }
#pragma unroll
            for (int nt = 0; nt < 16; ++nt) {
                bf16x8 b = *(const bf16x8*)&Bs[cur][((size_t)lq * 256 + nt * 16 + lm) * 8];
                acc[nt] = __builtin_amdgcn_mfma_f32_16x16x32_bf16(acur, b, acc[nt], 0, 0, 0);
            }
            __syncthreads();
            acur = anext;
        }
        // epilogue A: -> Xl (wave-private; swizzle byte ^= (row&7)<<4)
#pragma unroll
        for (int i = 0; i < 4; ++i) {
            int row = r0 + lq * 4 + i;
            if (row >= NN) continue;
            int ob = row * TT;
            int o0 = offsets[ob], o1 = offsets[ob + 1], o2 = offsets[ob + 2],
                o3 = offsets[ob + 3], o4 = offsets[ob + 4];
            float n0 = (float)(o1 - o0), n1 = (float)(o2 - o1),
                  n2 = (float)(o3 - o2), n3 = (float)(o4 - o3);
            int rl = lq * 4 + i;
            char* rbase = xlw + rl * 512;
            int swz = (rl & 7) << 4;
#pragma unroll
            for (int nt = 0; nt < 16; ++nt) {
                int col = nt * 16 + lm;
                float bias = n0 * b_msg[col] + n1 * b_msg[MM + col]
                           + n2 * b_msg[2 * MM + col] + n3 * b_msg[3 * MM + col];
                *(__bf16*)(rbase + ((col * 2) ^ swz)) =
                    (__bf16)fmaxf(acc[nt][i] + bias, 0.f);
            }
        }
    }

    // ---------------- phase B: GRU ----------------
    // stage (j=0, half=0) -> Bs[0] (Bs fully dead after phase A's final barrier)
#pragma unroll
    for (int i = 0; i < 6; ++i) {
        int q = i * 4 + wave;
        GLDS(WBj + (size_t)q * 512 + lane * 8, &Bs[0][q * 512]);
    }

    // A-fragments: msgs (cols 0-255) from Xl, h (cols 256-383) from hbc
    bf16x8 a[12];
    {
        char* rrow = xlw + lm * 512;
        int swz = (lm & 7) << 4;
#pragma unroll
        for (int c = 0; c < 8; ++c)
            a[c] = *(const bf16x8*)(rrow + ((c * 64 + lq * 16) ^ swz));
        const __bf16* hp = hbc + (size_t)arow * DD + lq * 8;
#pragma unroll
        for (int c2 = 0; c2 < 4; ++c2)
            a[8 + c2] = *(const bf16x8*)(hp + c2 * 32);
    }
    __syncthreads();   // (0,0) landed

#pragma unroll 1
    for (int j = 0; j < 8; ++j) {
        const __bf16* srcj = WBj + (size_t)j * 24576;
        int d = j * 16 + lm;
        int rb = r0 + lq * 4;
        f32x4 ar = {}, az = {}, an = {}, ah = {};

        // ---- phase 2j: stage (j,1)->buf1, prefetch hold, compute half0 from buf0 ----
#pragma unroll
        for (int i = 0; i < 6; ++i) {
            int q = i * 4 + wave;
            GLDS(srcj + 12288 + (size_t)q * 512 + lane * 8, &Bs[1][q * 512]);
        }
        float h0 = hf[(size_t)(rb + 0 < NN ? rb + 0 : NN - 1) * DD + d];
        float h1 = hf[(size_t)(rb + 1 < NN ? rb + 1 : NN - 1) * DD + d];
        float h2 = hf[(size_t)(rb + 2 < NN ? rb + 2 : NN - 1) * DD + d];
        float h3 = hf[(size_t)(rb + 3 < NN ? rb + 3 : NN - 1) * DD + d];
#pragma unroll
        for (int cc = 0; cc < 6; ++cc) {
            const __bf16* Bp = &Bs[0][(cc * 4 + lq) * 512 + lm * 8];
            bf16x8 br = *(const bf16x8*)(Bp);
            bf16x8 bz = *(const bf16x8*)(Bp + 128);
            bf16x8 bn = *(const bf16x8*)(Bp + 256);
            bf16x8 bh = *(const bf16x8*)(Bp + 384);
            ar = __builtin_amdgcn_mfma_f32_16x16x32_bf16(a[cc], br, ar, 0, 0, 0);
            az = __builtin_amdgcn_mfma_f32_16x16x32_bf16(a[cc], bz, az, 0, 0, 0);
            an = __builtin_amdgcn_mfma_f32_16x16x32_bf16(a[cc], bn, an, 0, 0, 0);
            ah = __builtin_amdgcn_mfma_f32_16x16x32_bf16(a[cc], bh, ah, 0, 0, 0);
        }
        __syncthreads();   // (j,1) landed; all waves done with buf0

        // ---- phase 2j+1: stage (j+1,0)->buf0 (if any), compute half1 from buf1 ----
        if (j < 7) {
#pragma unroll
            for (int i = 0; i < 6; ++i) {
                int q = i * 4 + wave;
                GLDS(srcj + 24576 + (size_t)q * 512 + lane * 8, &Bs[0][q * 512]);
            }
        }
#pragma unroll
        for (int cc = 0; cc < 6; ++cc) {
            const __bf16* Bp = &Bs[1][(cc * 4 + lq) * 512 + lm * 8];
            bf16x8 br = *(const bf16x8*)(Bp);
            bf16x8 bz = *(const bf16x8*)(Bp + 128);
            bf16x8 bn = *(const bf16x8*)(Bp + 256);
            bf16x8 bh = *(const bf16x8*)(Bp + 384);
            ar = __builtin_amdgcn_mfma_f32_16x16x32_bf16(a[6 + cc], br, ar, 0, 0, 0);
            az = __builtin_amdgcn_mfma_f32_16x16x32_bf16(a[6 + cc], bz, az, 0, 0, 0);
            an = __builtin_amdgcn_mfma_f32_16x16x32_bf16(a[6 + cc], bn, an, 0, 0, 0);
            ah = __builtin_amdgcn_mfma_f32_16x16x32_bf16(a[6 + cc], bh, ah, 0, 0, 0);
        }
        // ---- epilogue for j (registers + global only) ----
        float cbr = b512[d], cbz = b512[128 + d], cbn = b512[256 + d], cbh = b512[384 + d];
        float hv[4] = {h0, h1, h2, h3};
#pragma unroll
        for (int i = 0; i < 4; ++i) {
            int row = rb + i;
            if (row >= NN) continue;
            float pr  = ar[i] + cbr;
            float pz  = az[i] + cbz;
            float pin = an[i] + cbn;
            float phn = ah[i] + cbh;
            float r = fast_sigmoid(pr);
            float z = fast_sigmoid(pz);
            float nv = fast_tanh(pin + r * phn);
            float hnew = (1.f - z) * nv + z * hv[i];
            hf[(size_t)row * DD + d] = hnew;
            hbc[(size_t)row * DD + d] = (__bf16)hnew;
        }
        __syncthreads();   // (j+1,0) landed; all waves done with buf1
    }
}

// ================= readout =================
__global__ void attn_kernel(const float* __restrict__ hf, const float* __restrict__ w_gate,
                            const float* __restrict__ b_gate, float* __restrict__ attn) {
    int node = blockIdx.x * 4 + (threadIdx.x >> 6);
    int lane = threadIdx.x & 63;
    if (node >= NN) return;
    size_t base = (size_t)node * DD;
    float s = hf[base + lane * 2] * w_gate[lane * 2]
            + hf[base + lane * 2 + 1] * w_gate[lane * 2 + 1];
    for (int off = 32; off; off >>= 1) s += __shfl_down(s, off);
    if (lane == 0) attn[node] = 1.f / (1.f + expf(-(s + b_gate[0])));
}

__global__ void segsum_kernel(const int* __restrict__ goff, const float* __restrict__ attn,
                              const float* __restrict__ hf, float* __restrict__ sg,
                              float* __restrict__ asumg) {
    int g = blockIdx.x;
    int d = threadIdx.x;
    int beg = goff[g], end = goff[g + 1];
    float s = 0.f, asum = 0.f;
    for (int i = beg; i < end; ++i) {
        float a = attn[i];
        s += a * hf[(size_t)i * DD + d];
        if (d == 0) asum += a;
    }
    sg[g * DD + d] = s;
    if (d == 0) asumg[g] = asum;
}

__global__ void readout_kernel(const float* __restrict__ sg, const float* __restrict__ asumg,
                               const float* __restrict__ W_g, const float* __restrict__ b_g,
                               float* __restrict__ hgraph) {
    int g = blockIdx.x;
    int m = threadIdx.x;
    float acc = asumg[g] * b_g[m];
    for (int d = 0; d < DD; ++d) acc += sg[g * DD + d] * W_g[d * GHID + m];
    hgraph[g * GHID + m] = acc;
}

// ================= launch =================
extern "C" void kernel_launch(void* const* d_in, const int* in_sizes, int n_in,
                              void* d_out, int out_size, void* d_ws, size_t ws_size,
                              hipStream_t stream) {
    const int*   node_types = (const int*)d_in[0];
    const int*   edge_src   = (const int*)d_in[1];
    const int*   edge_dst   = (const int*)d_in[2];
    const int*   edge_type  = (const int*)d_in[3];
    const int*   node2graph = (const int*)d_in[4];
    const float* emb        = (const float*)d_in[5];
    const float* W_msg      = (const float*)d_in[6];
    const float* b_msg      = (const float*)d_in[7];
    const float* W_ih       = (const float*)d_in[8];
    const float* W_hh       = (const float*)d_in[9];
    const float* b_ih       = (const float*)d_in[10];
    const float* b_hh       = (const float*)d_in[11];
    const float* w_gate     = (const float*)d_in[12];
    const float* b_gate     = (const float*)d_in[13];
    const float* W_g        = (const float*)d_in[14];
    const float* b_g        = (const float*)d_in[15];

    float* hf     = (float*)d_out;
    float* hgraph = hf + (size_t)NN * DD;

    char* ws = (char*)d_ws;
    size_t off = 0;
    auto alloc = [&](size_t bytes) -> char* {
        char* p = ws + off;
        off += (bytes + 255) & ~(size_t)255;
        return p;
    };
    __bf16* X       = (__bf16*)alloc((size_t)NN * 512 * 2);   // 51.2 MB
    __bf16* hbc     = (__bf16*)alloc((size_t)NN * DD * 2);    // 12.8 MB compact h
    __bf16* WK      = (__bf16*)alloc((size_t)16 * 4 * 256 * 8 * 2);
    __bf16* WB      = (__bf16*)alloc((size_t)12 * 4 * 512 * 8 * 2);
    float*  b512    = (float*)alloc(512 * 4);
    float*  attn    = (float*)alloc((size_t)NN * 4);
    float*  sg      = (float*)alloc((size_t)NG * DD * 4);
    float*  asumg   = (float*)alloc((size_t)NG * 4);
    int*    counts  = (int*)alloc((size_t)(NKEY + 1) * 4);
    int*    offsets = (int*)alloc((size_t)(NKEY + 1) * 4);
    int*    cursor  = (int*)alloc((size_t)(NKEY + 1) * 4);
    int*    bsum    = (int*)alloc((size_t)1024 * 4);
    int*    elist   = (int*)alloc((size_t)NE * 4);
    int*    gcounts = (int*)alloc((size_t)(NG + 1) * 4);
    int*    goff    = (int*)alloc((size_t)(NG + 1) * 4);
    int*    gbsum   = (int*)alloc((size_t)8 * 4);

    hipMemsetAsync(counts, 0, (NKEY + 1) * 4, stream);
    hipMemsetAsync(gcounts, 0, (NG + 1) * 4, stream);

    build_WK<<<(16 * 4 * 256 * 8 + 255) / 256, 256, 0, stream>>>(W_msg, WK);
    build_WBj<<<(12 * 4 * 512 * 8 + 255) / 256, 256, 0, stream>>>(W_ih, W_hh, WB);
    build_bias512<<<2, 256, 0, stream>>>(b_ih, b_hh, b512);
    embed_kernel<<<(NN * DD + 255) / 256, 256, 0, stream>>>(node_types, emb, hf, hbc);

    int nbE = (NKEY + 255) / 256;
    hist_kernel<<<(NE + 255) / 256, 256, 0, stream>>>(edge_src, edge_type, counts);
    scan1<<<nbE, 256, 0, stream>>>(counts, offsets, bsum, NKEY);
    scan2<<<1, 1024, 0, stream>>>(bsum, nbE, offsets, NKEY);
    scan3<<<nbE, 256, 0, stream>>>(offsets, bsum, cursor, NKEY);
    fill_kernel<<<(NE + 255) / 256, 256, 0, stream>>>(edge_src, edge_dst, edge_type, cursor, elist);

    int nbG = (NG + 255) / 256;
    ghist_kernel<<<(NN + 255) / 256, 256, 0, stream>>>(node2graph, gcounts);
    scan1<<<nbG, 256, 0, stream>>>(gcounts, goff, gbsum, NG);
    scan2<<<1, 1024, 0, stream>>>(gbsum, nbG, goff, NG);
    scan3<<<nbG, 256, 0, stream>>>(goff, gbsum, (int*)nullptr, NG);

    int rt = (NN + 63) / 64;  // 782
    for (int p = 0; p < NPASS; ++p) {
        agg4<<<(NN + 3) / 4, 256, 0, stream>>>(offsets, elist, hbc, X);
        msgs_gru<<<rt, 256, 0, stream>>>(X, WK, b_msg, offsets, WB, b512, hf, hbc);
    }

    attn_kernel<<<(NN + 3) / 4, 256, 0, stream>>>(hf, w_gate, b_gate, attn);
    segsum_kernel<<<NG, 128, 0, stream>>>(goff, attn, hf, sg, asumg);
    readout_kernel<<<NG, GHID, 0, stream>>>(sg, asumg, W_g, b_g, hgraph);
}

// Round 11
// 741.984 us; speedup vs baseline: 1.4127x; 1.0205x over previous
//
#include <hip/hip_runtime.h>
#include <hip/hip_bf16.h>

#define NN 50000
#define NE 800000
#define NG 512
#define DD 128
#define MM 256
#define TT 4
#define NPASS 4
#define GHID 256
#define NKEY (NN * TT)          // CSR keys: src*4 + type

typedef __bf16 bf16x2 __attribute__((ext_vector_type(2)));
typedef __bf16 bf16x4 __attribute__((ext_vector_type(4)));
typedef __bf16 bf16x8 __attribute__((ext_vector_type(8)));
typedef float f32x4 __attribute__((ext_vector_type(4)));

__device__ __forceinline__ float fast_sigmoid(float x) {
    return __builtin_amdgcn_rcpf(1.f + __expf(-x));
}
__device__ __forceinline__ float fast_tanh(float x) {
    float e2 = __expf(2.f * x);
    return 1.f - 2.f * __builtin_amdgcn_rcpf(e2 + 1.f);
}

#define GLDS(SRC, DST) \
    __builtin_amdgcn_global_load_lds( \
        (const __attribute__((address_space(1))) unsigned int*)(SRC), \
        (__attribute__((address_space(3))) unsigned int*)(DST), 16, 0, 0)

// ================= setup: swizzled weights =================
__global__ void build_WK(const float* __restrict__ W_msg, __bf16* __restrict__ WK) {
    int i = blockIdx.x * 256 + threadIdx.x;           // 131072
    if (i >= 16 * 4 * 256 * 8) return;
    int j = i & 7, col = (i >> 3) & 255, g = i >> 11; // g=c*4+lq
    int k = g * 8 + j;
    WK[i] = (__bf16)W_msg[k * 256 + col];
}

// j-major GRU weight layout: WBj[j][c][lq][gate][lm][e]
// value = B[k=(c*4+lq)*8+e][col = gate*128 + j*16 + lm]
// K rows 0..255 (msgs) are permuted by pi to match the swapped-phase-A
// register layout: slot k holds msg column pi_inv(k).
__global__ void build_WBj(const float* __restrict__ W_ih, const float* __restrict__ W_hh,
                          __bf16* __restrict__ WB) {
    int i = blockIdx.x * 256 + threadIdx.x;           // 196608
    if (i >= 8 * 12 * 4 * 4 * 16 * 8) return;
    int low = i & 127;
    int lm = low >> 3, e = low & 7;
    int rest = i >> 7;
    int g  = rest & 3;
    int lq = (rest >> 2) & 3;
    int jc = rest >> 4;          // j*12 + c
    int c  = jc % 12;
    int j  = jc / 12;
    int k   = (c * 4 + lq) * 8 + e;     // 0..383
    int col = g * 128 + j * 16 + lm;    // 0..511
    int korig = k;
    if (k < 256) {                      // pi_inv: k=(c2,lq2,e2) -> col=nt*16+lq2*4+i2
        int c2 = k >> 5, lq2 = (k >> 3) & 3, e2 = k & 7;
        int nt = c2 * 2 + (e2 >> 2), i2 = e2 & 3;
        korig = nt * 16 + lq2 * 4 + i2;
    }
    float v = 0.f;
    if (col < 256) {
        v = (k < 256) ? W_ih[col * 256 + korig] : W_hh[col * 128 + (k - 256)];
    } else if (col < 384) {
        if (k < 256) v = W_ih[col * 256 + korig];
    } else {
        if (k >= 256) v = W_hh[(col - 128) * 128 + (k - 256)];
    }
    WB[i] = (__bf16)v;
}

__global__ void build_bias512(const float* __restrict__ b_ih, const float* __restrict__ b_hh,
                              float* __restrict__ b512) {
    int c = blockIdx.x * 256 + threadIdx.x;
    if (c >= 512) return;
    float v;
    if (c < 256) v = b_ih[c] + b_hh[c];
    else if (c < 384) v = b_ih[c];
    else v = b_hh[c - 128];
    b512[c] = v;
}

// ================= embedding =================
__global__ void embed_kernel(const int* __restrict__ node_types,
                             const float* __restrict__ emb,
                             float* __restrict__ hf, __bf16* __restrict__ hbc) {
    int t = blockIdx.x * 256 + threadIdx.x;
    if (t >= NN * DD) return;
    int node = t >> 7;
    float v = emb[node_types[node] * DD + (t & 127)];
    hf[t] = v;
    hbc[t] = (__bf16)v;
}

// ================= CSR build (keyed by src*4+type) =================
__global__ void hist_kernel(const int* __restrict__ src, const int* __restrict__ et,
                            int* __restrict__ counts) {
    int e = blockIdx.x * 256 + threadIdx.x;
    if (e < NE) atomicAdd(&counts[src[e] * TT + et[e]], 1);
}

__global__ void ghist_kernel(const int* __restrict__ n2g, int* __restrict__ gcounts) {
    int i = blockIdx.x * 256 + threadIdx.x;
    if (i < NN) atomicAdd(&gcounts[n2g[i]], 1);
}

__global__ void scan1(const int* __restrict__ counts, int* __restrict__ offsets,
                      int* __restrict__ bsum, int n) {
    __shared__ int sm[256];
    int i = blockIdx.x * 256 + threadIdx.x;
    int v = (i < n) ? counts[i] : 0;
    sm[threadIdx.x] = v;
    __syncthreads();
    for (int off = 1; off < 256; off <<= 1) {
        int t = (threadIdx.x >= off) ? sm[threadIdx.x - off] : 0;
        __syncthreads();
        sm[threadIdx.x] += t;
        __syncthreads();
    }
    if (i < n) offsets[i] = sm[threadIdx.x] - v;
    if (threadIdx.x == 255) bsum[blockIdx.x] = sm[255];
}

__global__ void scan2(int* __restrict__ bsum, int nb, int* __restrict__ offsets, int n) {
    __shared__ int sm[1024];
    int v = (threadIdx.x < nb) ? bsum[threadIdx.x] : 0;
    sm[threadIdx.x] = v;
    __syncthreads();
    for (int off = 1; off < 1024; off <<= 1) {
        int t = (threadIdx.x >= off) ? sm[threadIdx.x - off] : 0;
        __syncthreads();
        sm[threadIdx.x] += t;
        __syncthreads();
    }
    if (threadIdx.x < nb) bsum[threadIdx.x] = sm[threadIdx.x] - v;
    if (threadIdx.x == 1023) offsets[n] = sm[1023];
}

__global__ void scan3(int* __restrict__ offsets, const int* __restrict__ bsum,
                      int* __restrict__ cursor, int n) {
    int i = blockIdx.x * 256 + threadIdx.x;
    if (i < n) {
        int o = offsets[i] + bsum[blockIdx.x];
        offsets[i] = o;
        if (cursor) cursor[i] = o;
    }
}

__global__ void fill_kernel(const int* __restrict__ src, const int* __restrict__ dst,
                            const int* __restrict__ et, int* __restrict__ cursor,
                            int* __restrict__ elist) {
    int e = blockIdx.x * 256 + threadIdx.x;
    if (e >= NE) return;
    int pos = atomicAdd(&cursor[src[e] * TT + et[e]], 1);
    elist[pos] = dst[e];
}

// ================= aggregation: wave per SRC ROW (all 4 types), branchless batch-0 =====
__global__ void agg4(const int* __restrict__ offsets, const int* __restrict__ elist,
                     const __bf16* __restrict__ hbc, __bf16* __restrict__ X) {
    int row = blockIdx.x * 4 + (threadIdx.x >> 6);
    if (row >= NN) return;
    int lane = threadIdx.x & 63;
    const __bf16* hb = hbc + lane * 2;
    int ob = row * TT;
    int o0 = __builtin_amdgcn_readfirstlane(offsets[ob]);
    int o1 = __builtin_amdgcn_readfirstlane(offsets[ob + 1]);
    int o2 = __builtin_amdgcn_readfirstlane(offsets[ob + 2]);
    int o3 = __builtin_amdgcn_readfirstlane(offsets[ob + 3]);
    int o4 = __builtin_amdgcn_readfirstlane(offsets[ob + 4]);
    int begs[4] = {o0, o1, o2, o3};
    int ends[4] = {o1, o2, o3, o4};

    float ax[4] = {0.f, 0.f, 0.f, 0.f};
    float ay[4] = {0.f, 0.f, 0.f, 0.f};

    // ---- batch 0: 8 clamped gathers x 4 types, ALL issued before any accumulate ----
    bf16x2 v[4][8];
    int nb[4];
#pragma unroll
    for (int t = 0; t < 4; ++t) {
        int beg = begs[t], end = ends[t];
        nb[t] = end - beg;
        int e1 = end - 1;
        if (e1 < 0) e1 = 0;
        int idx[8];
#pragma unroll
        for (int k = 0; k < 8; ++k) {
            int p = beg + k; if (p > e1) p = e1;
            idx[k] = elist[p];
        }
#pragma unroll
        for (int k = 0; k < 8; ++k)
            v[t][k] = *(const bf16x2*)(hb + (size_t)idx[k] * DD);
    }
#pragma unroll
    for (int t = 0; t < 4; ++t) {
#pragma unroll
        for (int k = 0; k < 8; ++k) {
            float m = (nb[t] > k) ? 1.f : 0.f;
            ax[t] += m * (float)v[t][k].x;
            ay[t] += m * (float)v[t][k].y;
        }
    }

    // ---- tails (deg > 8 per type, rare) ----
#pragma unroll
    for (int t = 0; t < 4; ++t) {
        int end = ends[t];
        for (int base = begs[t] + 8; base < end; base += 8) {
            int nb2 = end - base; if (nb2 > 8) nb2 = 8;
            int e1 = end - 1;
            int idx[8];
#pragma unroll
            for (int k = 0; k < 8; ++k) {
                int p = base + k; if (p > e1) p = e1;
                idx[k] = elist[p];
            }
            bf16x2 tv[8];
#pragma unroll
            for (int k = 0; k < 8; ++k)
                tv[k] = *(const bf16x2*)(hb + (size_t)idx[k] * DD);
#pragma unroll
            for (int k = 0; k < 8; ++k) {
                float m = (nb2 > k) ? 1.f : 0.f;
                ax[t] += m * (float)tv[k].x;
                ay[t] += m * (float)tv[k].y;
            }
        }
    }

#pragma unroll
    for (int t = 0; t < 4; ++t) {
        bf16x2 o;
        o.x = (__bf16)ax[t];
        o.y = (__bf16)ay[t];
        *(bf16x2*)(X + (size_t)(ob + t) * 128 + lane * 2) = o;
    }
}

// ================= FUSED msgs GEMM + GRU GEMM (register handoff) =================
// Phase A computes SWAPPED mfma(wk, x): lane(lm,lq) holds M[lm][nt*16+lq*4+i]
// -> row lm is lane-local, so msgs A-frags for phase B come straight from
// registers; the column interleave is absorbed by WBj's K-permutation pi.
__global__ __launch_bounds__(256, 3)
void msgs_gru(const __bf16* __restrict__ X, const __bf16* __restrict__ WK,
              const float* __restrict__ b_msg, const int* __restrict__ offsets,
              const __bf16* __restrict__ WBj, const float* __restrict__ b512,
              float* __restrict__ hf, __bf16* __restrict__ hbc) {
    __shared__ __bf16 Bs[2][12288];   // 48 KB total -> 3 blocks/CU
    int tid = threadIdx.x, wave = tid >> 6, lane = tid & 63;
    int lm = lane & 15, lq = lane >> 4;
    int r0 = blockIdx.x * 64 + wave * 16;
    int arow = r0 + lm; if (arow >= NN) arow = NN - 1;

    bf16x8 a[12];   // phase-B A-fragments: [0..7]=msgs, [8..11]=h

    // ---------------- phase A: M = relu(X @ WK + deg-bias), swapped operands ----------------
    {
        const __bf16* Ap = X + (size_t)arow * 512 + lq * 8;
#pragma unroll
        for (int i = 0; i < 4; ++i) {
            int q = i * 4 + wave;
            GLDS(WK + (size_t)q * 512 + lane * 8, &Bs[0][q * 512]);
        }
        bf16x8 acur = *(const bf16x8*)(Ap);
        f32x4 acc[16] = {};
        __syncthreads();    // stage 0 landed

#pragma unroll 1
        for (int c = 0; c < 16; ++c) {
            int cur = c & 1;
            bf16x8 anext = acur;
            if (c < 15) {
                const __bf16* src = WK + (size_t)(c + 1) * 8192;
#pragma unroll
                for (int i = 0; i < 4; ++i) {
                    int q = i * 4 + wave;
                    GLDS(src + (size_t)q * 512 + lane * 8, &Bs[cur ^ 1][q * 512]);
                }
                anext = *(const bf16x8*)(Ap + (c + 1) * 32);
            }
#pragma unroll
            for (int nt = 0; nt < 16; ++nt) {
                bf16x8 b = *(const bf16x8*)&Bs[cur][((size_t)lq * 256 + nt * 16 + lm) * 8];
                // SWAPPED: A = WK frag, B = X frag  ->  acc[nt] = M^T tile
                acc[nt] = __builtin_amdgcn_mfma_f32_16x16x32_bf16(b, acur, acc[nt], 0, 0, 0);
            }
            __syncthreads();
            acur = anext;
        }
        // epilogue A (registers only): bias by row-lm degrees, relu, pack to bf16x8
        int ob2 = arow * TT;
        int q0 = offsets[ob2], q1 = offsets[ob2 + 1], q2 = offsets[ob2 + 2],
            q3 = offsets[ob2 + 3], q4 = offsets[ob2 + 4];
        float n0 = (float)(q1 - q0), n1 = (float)(q2 - q1),
              n2 = (float)(q3 - q2), n3 = (float)(q4 - q3);
#pragma unroll
        for (int c = 0; c < 8; ++c) {
#pragma unroll
            for (int e = 0; e < 8; ++e) {
                int nt = c * 2 + (e >> 2), ii = e & 3;
                int col = nt * 16 + lq * 4 + ii;
                float bias = n0 * b_msg[col] + n1 * b_msg[MM + col]
                           + n2 * b_msg[2 * MM + col] + n3 * b_msg[3 * MM + col];
                a[c][e] = (__bf16)fmaxf(acc[nt][ii] + bias, 0.f);
            }
        }
    }

    // ---------------- phase B: GRU ----------------
    // stage (j=0, half=0) -> Bs[0] (Bs dead after phase A's final barrier)
#pragma unroll
    for (int i = 0; i < 6; ++i) {
        int q = i * 4 + wave;
        GLDS(WBj + (size_t)q * 512 + lane * 8, &Bs[0][q * 512]);
    }
    {
        const __bf16* hp = hbc + (size_t)arow * DD + lq * 8;
#pragma unroll
        for (int c2 = 0; c2 < 4; ++c2)
            a[8 + c2] = *(const bf16x8*)(hp + c2 * 32);
    }
    __syncthreads();   // (0,0) landed

#pragma unroll 1
    for (int j = 0; j < 8; ++j) {
        const __bf16* srcj = WBj + (size_t)j * 24576;
        int d = j * 16 + lm;
        int rb = r0 + lq * 4;
        f32x4 ar = {}, az = {}, an = {}, ah = {};

        // ---- phase 2j: stage (j,1)->buf1, prefetch hold, compute half0 from buf0 ----
#pragma unroll
        for (int i = 0; i < 6; ++i) {
            int q = i * 4 + wave;
            GLDS(srcj + 12288 + (size_t)q * 512 + lane * 8, &Bs[1][q * 512]);
        }
        float h0 = hf[(size_t)(rb + 0 < NN ? rb + 0 : NN - 1) * DD + d];
        float h1 = hf[(size_t)(rb + 1 < NN ? rb + 1 : NN - 1) * DD + d];
        float h2 = hf[(size_t)(rb + 2 < NN ? rb + 2 : NN - 1) * DD + d];
        float h3 = hf[(size_t)(rb + 3 < NN ? rb + 3 : NN - 1) * DD + d];
#pragma unroll
        for (int cc = 0; cc < 6; ++cc) {
            const __bf16* Bp = &Bs[0][(cc * 4 + lq) * 512 + lm * 8];
            bf16x8 br = *(const bf16x8*)(Bp);
            bf16x8 bz = *(const bf16x8*)(Bp + 128);
            bf16x8 bn = *(const bf16x8*)(Bp + 256);
            bf16x8 bh = *(const bf16x8*)(Bp + 384);
            ar = __builtin_amdgcn_mfma_f32_16x16x32_bf16(a[cc], br, ar, 0, 0, 0);
            az = __builtin_amdgcn_mfma_f32_16x16x32_bf16(a[cc], bz, az, 0, 0, 0);
            an = __builtin_amdgcn_mfma_f32_16x16x32_bf16(a[cc], bn, an, 0, 0, 0);
            ah = __builtin_amdgcn_mfma_f32_16x16x32_bf16(a[cc], bh, ah, 0, 0, 0);
        }
        __syncthreads();   // (j,1) landed; all waves done with buf0

        // ---- phase 2j+1: stage (j+1,0)->buf0 (if any), compute half1 from buf1 ----
        if (j < 7) {
#pragma unroll
            for (int i = 0; i < 6; ++i) {
                int q = i * 4 + wave;
                GLDS(srcj + 24576 + (size_t)q * 512 + lane * 8, &Bs[0][q * 512]);
            }
        }
#pragma unroll
        for (int cc = 0; cc < 6; ++cc) {
            const __bf16* Bp = &Bs[1][(cc * 4 + lq) * 512 + lm * 8];
            bf16x8 br = *(const bf16x8*)(Bp);
            bf16x8 bz = *(const bf16x8*)(Bp + 128);
            bf16x8 bn = *(const bf16x8*)(Bp + 256);
            bf16x8 bh = *(const bf16x8*)(Bp + 384);
            ar = __builtin_amdgcn_mfma_f32_16x16x32_bf16(a[6 + cc], br, ar, 0, 0, 0);
            az = __builtin_amdgcn_mfma_f32_16x16x32_bf16(a[6 + cc], bz, az, 0, 0, 0);
            an = __builtin_amdgcn_mfma_f32_16x16x32_bf16(a[6 + cc], bn, an, 0, 0, 0);
            ah = __builtin_amdgcn_mfma_f32_16x16x32_bf16(a[6 + cc], bh, ah, 0, 0, 0);
        }
        // ---- epilogue for j (registers + global only) ----
        float cbr = b512[d], cbz = b512[128 + d], cbn = b512[256 + d], cbh = b512[384 + d];
        float hv[4] = {h0, h1, h2, h3};
#pragma unroll
        for (int i = 0; i < 4; ++i) {
            int row = rb + i;
            if (row >= NN) continue;
            float pr  = ar[i] + cbr;
            float pz  = az[i] + cbz;
            float pin = an[i] + cbn;
            float phn = ah[i] + cbh;
            float r = fast_sigmoid(pr);
            float z = fast_sigmoid(pz);
            float nv = fast_tanh(pin + r * phn);
            float hnew = (1.f - z) * nv + z * hv[i];
            hf[(size_t)row * DD + d] = hnew;
            hbc[(size_t)row * DD + d] = (__bf16)hnew;
        }
        __syncthreads();   // (j+1,0) landed; all waves done with buf1
    }
}

// ================= readout =================
__global__ void attn_kernel(const float* __restrict__ hf, const float* __restrict__ w_gate,
                            const float* __restrict__ b_gate, float* __restrict__ attn) {
    int node = blockIdx.x * 4 + (threadIdx.x >> 6);
    int lane = threadIdx.x & 63;
    if (node >= NN) return;
    size_t base = (size_t)node * DD;
    float s = hf[base + lane * 2] * w_gate[lane * 2]
            + hf[base + lane * 2 + 1] * w_gate[lane * 2 + 1];
    for (int off = 32; off; off >>= 1) s += __shfl_down(s, off);
    if (lane == 0) attn[node] = 1.f / (1.f + expf(-(s + b_gate[0])));
}

__global__ void segsum_kernel(const int* __restrict__ goff, const float* __restrict__ attn,
                              const float* __restrict__ hf, float* __restrict__ sg,
                              float* __restrict__ asumg) {
    int g = blockIdx.x;
    int d = threadIdx.x;
    int beg = goff[g], end = goff[g + 1];
    float s = 0.f, asum = 0.f;
    for (int i = beg; i < end; ++i) {
        float a = attn[i];
        s += a * hf[(size_t)i * DD + d];
        if (d == 0) asum += a;
    }
    sg[g * DD + d] = s;
    if (d == 0) asumg[g] = asum;
}

__global__ void readout_kernel(const float* __restrict__ sg, const float* __restrict__ asumg,
                               const float* __restrict__ W_g, const float* __restrict__ b_g,
                               float* __restrict__ hgraph) {
    int g = blockIdx.x;
    int m = threadIdx.x;
    float acc = asumg[g] * b_g[m];
    for (int d = 0; d < DD; ++d) acc += sg[g * DD + d] * W_g[d * GHID + m];
    hgraph[g * GHID + m] = acc;
}

// ================= launch =================
extern "C" void kernel_launch(void* const* d_in, const int* in_sizes, int n_in,
                              void* d_out, int out_size, void* d_ws, size_t ws_size,
                              hipStream_t stream) {
    const int*   node_types = (const int*)d_in[0];
    const int*   edge_src   = (const int*)d_in[1];
    const int*   edge_dst   = (const int*)d_in[2];
    const int*   edge_type  = (const int*)d_in[3];
    const int*   node2graph = (const int*)d_in[4];
    const float* emb        = (const float*)d_in[5];
    const float* W_msg      = (const float*)d_in[6];
    const float* b_msg      = (const float*)d_in[7];
    const float* W_ih       = (const float*)d_in[8];
    const float* W_hh       = (const float*)d_in[9];
    const float* b_ih       = (const float*)d_in[10];
    const float* b_hh       = (const float*)d_in[11];
    const float* w_gate     = (const float*)d_in[12];
    const float* b_gate     = (const float*)d_in[13];
    const float* W_g        = (const float*)d_in[14];
    const float* b_g        = (const float*)d_in[15];

    float* hf     = (float*)d_out;
    float* hgraph = hf + (size_t)NN * DD;

    char* ws = (char*)d_ws;
    size_t off = 0;
    auto alloc = [&](size_t bytes) -> char* {
        char* p = ws + off;
        off += (bytes + 255) & ~(size_t)255;
        return p;
    };
    __bf16* X       = (__bf16*)alloc((size_t)NN * 512 * 2);   // 51.2 MB
    __bf16* hbc     = (__bf16*)alloc((size_t)NN * DD * 2);    // 12.8 MB compact h
    __bf16* WK      = (__bf16*)alloc((size_t)16 * 4 * 256 * 8 * 2);
    __bf16* WB      = (__bf16*)alloc((size_t)12 * 4 * 512 * 8 * 2);
    float*  b512    = (float*)alloc(512 * 4);
    float*  attn    = (float*)alloc((size_t)NN * 4);
    float*  sg      = (float*)alloc((size_t)NG * DD * 4);
    float*  asumg   = (float*)alloc((size_t)NG * 4);
    int*    counts  = (int*)alloc((size_t)(NKEY + 1) * 4);
    int*    offsets = (int*)alloc((size_t)(NKEY + 1) * 4);
    int*    cursor  = (int*)alloc((size_t)(NKEY + 1) * 4);
    int*    bsum    = (int*)alloc((size_t)1024 * 4);
    int*    elist   = (int*)alloc((size_t)NE * 4);
    int*    gcounts = (int*)alloc((size_t)(NG + 1) * 4);
    int*    goff    = (int*)alloc((size_t)(NG + 1) * 4);
    int*    gbsum   = (int*)alloc((size_t)8 * 4);

    hipMemsetAsync(counts, 0, (NKEY + 1) * 4, stream);
    hipMemsetAsync(gcounts, 0, (NG + 1) * 4, stream);

    build_WK<<<(16 * 4 * 256 * 8 + 255) / 256, 256, 0, stream>>>(W_msg, WK);
    build_WBj<<<(12 * 4 * 512 * 8 + 255) / 256, 256, 0, stream>>>(W_ih, W_hh, WB);
    build_bias512<<<2, 256, 0, stream>>>(b_ih, b_hh, b512);
    embed_kernel<<<(NN * DD + 255) / 256, 256, 0, stream>>>(node_types, emb, hf, hbc);

    int nbE = (NKEY + 255) / 256;
    hist_kernel<<<(NE + 255) / 256, 256, 0, stream>>>(edge_src, edge_type, counts);
    scan1<<<nbE, 256, 0, stream>>>(counts, offsets, bsum, NKEY);
    scan2<<<1, 1024, 0, stream>>>(bsum, nbE, offsets, NKEY);
    scan3<<<nbE, 256, 0, stream>>>(offsets, bsum, cursor, NKEY);
    fill_kernel<<<(NE + 255) / 256, 256, 0, stream>>>(edge_src, edge_dst, edge_type, cursor, elist);

    int nbG = (NG + 255) / 256;
    ghist_kernel<<<(NN + 255) / 256, 256, 0, stream>>>(node2graph, gcounts);
    scan1<<<nbG, 256, 0, stream>>>(gcounts, goff, gbsum, NG);
    scan2<<<1, 1024, 0, stream>>>(gbsum, nbG, goff, NG);
    scan3<<<nbG, 256, 0, stream>>>(goff, gbsum, (int*)nullptr, NG);

    int rt = (NN + 63) / 64;  // 782
    for (int p = 0; p < NPASS; ++p) {
        agg4<<<(NN + 3) / 4, 256, 0, stream>>>(offsets, elist, hbc, X);
        msgs_gru<<<rt, 256, 0, stream>>>(X, WK, b_msg, offsets, WB, b512, hf, hbc);
    }

    attn_kernel<<<(NN + 3) / 4, 256, 0, stream>>>(hf, w_gate, b_gate, attn);
    segsum_kernel<<<NG, 128, 0, stream>>>(goff, attn, hf, sg, asumg);
    readout_kernel<<<NG, GHID, 0, stream>>>(sg, asumg, W_g, b_g, hgraph);
}

// Round 12
// 669.332 us; speedup vs baseline: 1.5660x; 1.1085x over previous
//
#include <hip/hip_runtime.h>
#include <hip/hip_bf16.h>

#define NN 50000
#define NE 800000
#define NG 512
#define DD 128
#define MM 256
#define TT 4
#define NPASS 4
#define GHID 256
#define NKEY (NN * TT)          // CSR keys: src*4 + type

typedef __bf16 bf16x2 __attribute__((ext_vector_type(2)));
typedef __bf16 bf16x4 __attribute__((ext_vector_type(4)));
typedef __bf16 bf16x8 __attribute__((ext_vector_type(8)));
typedef float f32x4 __attribute__((ext_vector_type(4)));

__device__ __forceinline__ float fast_sigmoid(float x) {
    return __builtin_amdgcn_rcpf(1.f + __expf(-x));
}
__device__ __forceinline__ float fast_tanh(float x) {
    float e2 = __expf(2.f * x);
    return 1.f - 2.f * __builtin_amdgcn_rcpf(e2 + 1.f);
}

#define GLDS(SRC, DST) \
    __builtin_amdgcn_global_load_lds( \
        (const __attribute__((address_space(1))) unsigned int*)(SRC), \
        (__attribute__((address_space(3))) unsigned int*)(DST), 16, 0, 0)

// ================= setup: swizzled weights =================
__global__ void build_WK(const float* __restrict__ W_msg, __bf16* __restrict__ WK) {
    int i = blockIdx.x * 256 + threadIdx.x;           // 131072
    if (i >= 16 * 4 * 256 * 8) return;
    int j = i & 7, col = (i >> 3) & 255, g = i >> 11; // g=c*4+lq
    int k = g * 8 + j;
    WK[i] = (__bf16)W_msg[k * 256 + col];
}

// j-major GRU weight layout: WBj[j][c][lq][gate][lm][e]
// value = B[k=(c*4+lq)*8+e][col = gate*128 + j*16 + lm]
// K rows 0..255 (msgs) are permuted by pi to match the swapped-phase-A
// register layout: slot k holds msg column pi_inv(k).
__global__ void build_WBj(const float* __restrict__ W_ih, const float* __restrict__ W_hh,
                          __bf16* __restrict__ WB) {
    int i = blockIdx.x * 256 + threadIdx.x;           // 196608
    if (i >= 8 * 12 * 4 * 4 * 16 * 8) return;
    int low = i & 127;
    int lm = low >> 3, e = low & 7;
    int rest = i >> 7;
    int g  = rest & 3;
    int lq = (rest >> 2) & 3;
    int jc = rest >> 4;          // j*12 + c
    int c  = jc % 12;
    int j  = jc / 12;
    int k   = (c * 4 + lq) * 8 + e;     // 0..383
    int col = g * 128 + j * 16 + lm;    // 0..511
    int korig = k;
    if (k < 256) {                      // pi_inv: k=(c2,lq2,e2) -> col=nt*16+lq2*4+i2
        int c2 = k >> 5, lq2 = (k >> 3) & 3, e2 = k & 7;
        int nt = c2 * 2 + (e2 >> 2), i2 = e2 & 3;
        korig = nt * 16 + lq2 * 4 + i2;
    }
    float v = 0.f;
    if (col < 256) {
        v = (k < 256) ? W_ih[col * 256 + korig] : W_hh[col * 128 + (k - 256)];
    } else if (col < 384) {
        if (k < 256) v = W_ih[col * 256 + korig];
    } else {
        if (k >= 256) v = W_hh[(col - 128) * 128 + (k - 256)];
    }
    WB[i] = (__bf16)v;
}

__global__ void build_bias512(const float* __restrict__ b_ih, const float* __restrict__ b_hh,
                              float* __restrict__ b512) {
    int c = blockIdx.x * 256 + threadIdx.x;
    if (c >= 512) return;
    float v;
    if (c < 256) v = b_ih[c] + b_hh[c];
    else if (c < 384) v = b_ih[c];
    else v = b_hh[c - 128];
    b512[c] = v;
}

// ================= embedding =================
__global__ void embed_kernel(const int* __restrict__ node_types,
                             const float* __restrict__ emb,
                             float* __restrict__ hf, __bf16* __restrict__ hbc) {
    int t = blockIdx.x * 256 + threadIdx.x;
    if (t >= NN * DD) return;
    int node = t >> 7;
    float v = emb[node_types[node] * DD + (t & 127)];
    hf[t] = v;
    hbc[t] = (__bf16)v;
}

// ================= CSR build (keyed by src*4+type) =================
__global__ void hist_kernel(const int* __restrict__ src, const int* __restrict__ et,
                            int* __restrict__ counts) {
    int e = blockIdx.x * 256 + threadIdx.x;
    if (e < NE) atomicAdd(&counts[src[e] * TT + et[e]], 1);
}

__global__ void ghist_kernel(const int* __restrict__ n2g, int* __restrict__ gcounts) {
    int i = blockIdx.x * 256 + threadIdx.x;
    if (i < NN) atomicAdd(&gcounts[n2g[i]], 1);
}

__global__ void scan1(const int* __restrict__ counts, int* __restrict__ offsets,
                      int* __restrict__ bsum, int n) {
    __shared__ int sm[256];
    int i = blockIdx.x * 256 + threadIdx.x;
    int v = (i < n) ? counts[i] : 0;
    sm[threadIdx.x] = v;
    __syncthreads();
    for (int off = 1; off < 256; off <<= 1) {
        int t = (threadIdx.x >= off) ? sm[threadIdx.x - off] : 0;
        __syncthreads();
        sm[threadIdx.x] += t;
        __syncthreads();
    }
    if (i < n) offsets[i] = sm[threadIdx.x] - v;
    if (threadIdx.x == 255) bsum[blockIdx.x] = sm[255];
}

__global__ void scan2(int* __restrict__ bsum, int nb, int* __restrict__ offsets, int n) {
    __shared__ int sm[1024];
    int v = (threadIdx.x < nb) ? bsum[threadIdx.x] : 0;
    sm[threadIdx.x] = v;
    __syncthreads();
    for (int off = 1; off < 1024; off <<= 1) {
        int t = (threadIdx.x >= off) ? sm[threadIdx.x - off] : 0;
        __syncthreads();
        sm[threadIdx.x] += t;
        __syncthreads();
    }
    if (threadIdx.x < nb) bsum[threadIdx.x] = sm[threadIdx.x] - v;
    if (threadIdx.x == 1023) offsets[n] = sm[1023];
}

__global__ void scan3(int* __restrict__ offsets, const int* __restrict__ bsum,
                      int* __restrict__ cursor, int n) {
    int i = blockIdx.x * 256 + threadIdx.x;
    if (i < n) {
        int o = offsets[i] + bsum[blockIdx.x];
        offsets[i] = o;
        if (cursor) cursor[i] = o;
    }
}

__global__ void fill_kernel(const int* __restrict__ src, const int* __restrict__ dst,
                            const int* __restrict__ et, int* __restrict__ cursor,
                            int* __restrict__ elist) {
    int e = blockIdx.x * 256 + threadIdx.x;
    if (e >= NE) return;
    int pos = atomicAdd(&cursor[src[e] * TT + et[e]], 1);
    elist[pos] = dst[e];
}

// ================= aggregation: wave per SRC ROW (all 4 types), branchless batch-0 =====
__global__ void agg4(const int* __restrict__ offsets, const int* __restrict__ elist,
                     const __bf16* __restrict__ hbc, __bf16* __restrict__ X) {
    int row = blockIdx.x * 4 + (threadIdx.x >> 6);
    if (row >= NN) return;
    int lane = threadIdx.x & 63;
    const __bf16* hb = hbc + lane * 2;
    int ob = row * TT;
    int o0 = __builtin_amdgcn_readfirstlane(offsets[ob]);
    int o1 = __builtin_amdgcn_readfirstlane(offsets[ob + 1]);
    int o2 = __builtin_amdgcn_readfirstlane(offsets[ob + 2]);
    int o3 = __builtin_amdgcn_readfirstlane(offsets[ob + 3]);
    int o4 = __builtin_amdgcn_readfirstlane(offsets[ob + 4]);
    int begs[4] = {o0, o1, o2, o3};
    int ends[4] = {o1, o2, o3, o4};

    float ax[4] = {0.f, 0.f, 0.f, 0.f};
    float ay[4] = {0.f, 0.f, 0.f, 0.f};

    // ---- batch 0: 8 clamped gathers x 4 types, ALL issued before any accumulate ----
    bf16x2 v[4][8];
    int nb[4];
#pragma unroll
    for (int t = 0; t < 4; ++t) {
        int beg = begs[t], end = ends[t];
        nb[t] = end - beg;
        int e1 = end - 1;
        if (e1 < 0) e1 = 0;
        int idx[8];
#pragma unroll
        for (int k = 0; k < 8; ++k) {
            int p = beg + k; if (p > e1) p = e1;
            idx[k] = elist[p];
        }
#pragma unroll
        for (int k = 0; k < 8; ++k)
            v[t][k] = *(const bf16x2*)(hb + (size_t)idx[k] * DD);
    }
#pragma unroll
    for (int t = 0; t < 4; ++t) {
#pragma unroll
        for (int k = 0; k < 8; ++k) {
            float m = (nb[t] > k) ? 1.f : 0.f;
            ax[t] += m * (float)v[t][k].x;
            ay[t] += m * (float)v[t][k].y;
        }
    }

    // ---- tails (deg > 8 per type, rare) ----
#pragma unroll
    for (int t = 0; t < 4; ++t) {
        int end = ends[t];
        for (int base = begs[t] + 8; base < end; base += 8) {
            int nb2 = end - base; if (nb2 > 8) nb2 = 8;
            int e1 = end - 1;
            int idx[8];
#pragma unroll
            for (int k = 0; k < 8; ++k) {
                int p = base + k; if (p > e1) p = e1;
                idx[k] = elist[p];
            }
            bf16x2 tv[8];
#pragma unroll
            for (int k = 0; k < 8; ++k)
                tv[k] = *(const bf16x2*)(hb + (size_t)idx[k] * DD);
#pragma unroll
            for (int k = 0; k < 8; ++k) {
                float m = (nb2 > k) ? 1.f : 0.f;
                ax[t] += m * (float)tv[k].x;
                ay[t] += m * (float)tv[k].y;
            }
        }
    }

#pragma unroll
    for (int t = 0; t < 4; ++t) {
        bf16x2 o;
        o.x = (__bf16)ax[t];
        o.y = (__bf16)ay[t];
        *(bf16x2*)(X + (size_t)(ob + t) * 128 + lane * 2) = o;
    }
}

// ================= FUSED msgs GEMM + GRU GEMM (register handoff, 8-wave block) ======
// 512 threads = 8 waves = 128 rows/block; Bs (48 KB) shared by all 8 waves ->
// staging bytes + barrier round-trips amortized over 2x the FLOPs vs 4-wave.
__global__ __launch_bounds__(512, 4)
void msgs_gru(const __bf16* __restrict__ X, const __bf16* __restrict__ WK,
              const float* __restrict__ b_msg, const int* __restrict__ offsets,
              const __bf16* __restrict__ WBj, const float* __restrict__ b512,
              float* __restrict__ hf, __bf16* __restrict__ hbc) {
    __shared__ __bf16 Bs[2][12288];   // 48 KB total -> 3 blocks/CU
    int tid = threadIdx.x, wave = tid >> 6, lane = tid & 63;
    int lm = lane & 15, lq = lane >> 4;
    int r0 = blockIdx.x * 128 + wave * 16;
    int arow = r0 + lm; if (arow >= NN) arow = NN - 1;

    bf16x8 a[12];   // phase-B A-fragments: [0..7]=msgs, [8..11]=h

    // ---------------- phase A: M = relu(X @ WK + deg-bias), swapped operands ----------------
    {
        const __bf16* Ap = X + (size_t)arow * 512 + lq * 8;
#pragma unroll
        for (int i = 0; i < 2; ++i) {
            int q = i * 8 + wave;
            GLDS(WK + (size_t)q * 512 + lane * 8, &Bs[0][q * 512]);
        }
        bf16x8 acur = *(const bf16x8*)(Ap);
        f32x4 acc[16] = {};
        __syncthreads();    // stage 0 landed

#pragma unroll 1
        for (int c = 0; c < 16; ++c) {
            int cur = c & 1;
            bf16x8 anext = acur;
            if (c < 15) {
                const __bf16* src = WK + (size_t)(c + 1) * 8192;
#pragma unroll
                for (int i = 0; i < 2; ++i) {
                    int q = i * 8 + wave;
                    GLDS(src + (size_t)q * 512 + lane * 8, &Bs[cur ^ 1][q * 512]);
                }
                anext = *(const bf16x8*)(Ap + (c + 1) * 32);
            }
#pragma unroll
            for (int nt = 0; nt < 16; ++nt) {
                bf16x8 b = *(const bf16x8*)&Bs[cur][((size_t)lq * 256 + nt * 16 + lm) * 8];
                // SWAPPED: A = WK frag, B = X frag  ->  acc[nt] = M^T tile
                acc[nt] = __builtin_amdgcn_mfma_f32_16x16x32_bf16(b, acur, acc[nt], 0, 0, 0);
            }
            __syncthreads();
            acur = anext;
        }
        // epilogue A (registers only): bias by row-lm degrees, relu, pack to bf16x8
        int ob2 = arow * TT;
        int q0 = offsets[ob2], q1 = offsets[ob2 + 1], q2 = offsets[ob2 + 2],
            q3 = offsets[ob2 + 3], q4 = offsets[ob2 + 4];
        float n0 = (float)(q1 - q0), n1 = (float)(q2 - q1),
              n2 = (float)(q3 - q2), n3 = (float)(q4 - q3);
#pragma unroll
        for (int c = 0; c < 8; ++c) {
#pragma unroll
            for (int e = 0; e < 8; ++e) {
                int nt = c * 2 + (e >> 2), ii = e & 3;
                int col = nt * 16 + lq * 4 + ii;
                float bias = n0 * b_msg[col] + n1 * b_msg[MM + col]
                           + n2 * b_msg[2 * MM + col] + n3 * b_msg[3 * MM + col];
                a[c][e] = (__bf16)fmaxf(acc[nt][ii] + bias, 0.f);
            }
        }
    }

    // ---------------- phase B: GRU ----------------
    // stage (j=0, half=0) -> Bs[0] (Bs dead after phase A's final barrier)
#pragma unroll
    for (int i = 0; i < 3; ++i) {
        int q = i * 8 + wave;
        GLDS(WBj + (size_t)q * 512 + lane * 8, &Bs[0][q * 512]);
    }
    {
        const __bf16* hp = hbc + (size_t)arow * DD + lq * 8;
#pragma unroll
        for (int c2 = 0; c2 < 4; ++c2)
            a[8 + c2] = *(const bf16x8*)(hp + c2 * 32);
    }
    __syncthreads();   // (0,0) landed

#pragma unroll 1
    for (int j = 0; j < 8; ++j) {
        const __bf16* srcj = WBj + (size_t)j * 24576;
        int d = j * 16 + lm;
        int rb = r0 + lq * 4;
        f32x4 ar = {}, az = {}, an = {}, ah = {};

        // ---- phase 2j: stage (j,1)->buf1, prefetch hold, compute half0 from buf0 ----
#pragma unroll
        for (int i = 0; i < 3; ++i) {
            int q = i * 8 + wave;
            GLDS(srcj + 12288 + (size_t)q * 512 + lane * 8, &Bs[1][q * 512]);
        }
        float h0 = hf[(size_t)(rb + 0 < NN ? rb + 0 : NN - 1) * DD + d];
        float h1 = hf[(size_t)(rb + 1 < NN ? rb + 1 : NN - 1) * DD + d];
        float h2 = hf[(size_t)(rb + 2 < NN ? rb + 2 : NN - 1) * DD + d];
        float h3 = hf[(size_t)(rb + 3 < NN ? rb + 3 : NN - 1) * DD + d];
#pragma unroll
        for (int cc = 0; cc < 6; ++cc) {
            const __bf16* Bp = &Bs[0][(cc * 4 + lq) * 512 + lm * 8];
            bf16x8 br = *(const bf16x8*)(Bp);
            bf16x8 bz = *(const bf16x8*)(Bp + 128);
            bf16x8 bn = *(const bf16x8*)(Bp + 256);
            bf16x8 bh = *(const bf16x8*)(Bp + 384);
            ar = __builtin_amdgcn_mfma_f32_16x16x32_bf16(a[cc], br, ar, 0, 0, 0);
            az = __builtin_amdgcn_mfma_f32_16x16x32_bf16(a[cc], bz, az, 0, 0, 0);
            an = __builtin_amdgcn_mfma_f32_16x16x32_bf16(a[cc], bn, an, 0, 0, 0);
            ah = __builtin_amdgcn_mfma_f32_16x16x32_bf16(a[cc], bh, ah, 0, 0, 0);
        }
        __syncthreads();   // (j,1) landed; all waves done with buf0

        // ---- phase 2j+1: stage (j+1,0)->buf0 (if any), compute half1 from buf1 ----
        if (j < 7) {
#pragma unroll
            for (int i = 0; i < 3; ++i) {
                int q = i * 8 + wave;
                GLDS(srcj + 24576 + (size_t)q * 512 + lane * 8, &Bs[0][q * 512]);
            }
        }
#pragma unroll
        for (int cc = 0; cc < 6; ++cc) {
            const __bf16* Bp = &Bs[1][(cc * 4 + lq) * 512 + lm * 8];
            bf16x8 br = *(const bf16x8*)(Bp);
            bf16x8 bz = *(const bf16x8*)(Bp + 128);
            bf16x8 bn = *(const bf16x8*)(Bp + 256);
            bf16x8 bh = *(const bf16x8*)(Bp + 384);
            ar = __builtin_amdgcn_mfma_f32_16x16x32_bf16(a[6 + cc], br, ar, 0, 0, 0);
            az = __builtin_amdgcn_mfma_f32_16x16x32_bf16(a[6 + cc], bz, az, 0, 0, 0);
            an = __builtin_amdgcn_mfma_f32_16x16x32_bf16(a[6 + cc], bn, an, 0, 0, 0);
            ah = __builtin_amdgcn_mfma_f32_16x16x32_bf16(a[6 + cc], bh, ah, 0, 0, 0);
        }
        // ---- epilogue for j (registers + global only) ----
        float cbr = b512[d], cbz = b512[128 + d], cbn = b512[256 + d], cbh = b512[384 + d];
        float hv[4] = {h0, h1, h2, h3};
#pragma unroll
        for (int i = 0; i < 4; ++i) {
            int row = rb + i;
            if (row >= NN) continue;
            float pr  = ar[i] + cbr;
            float pz  = az[i] + cbz;
            float pin = an[i] + cbn;
            float phn = ah[i] + cbh;
            float r = fast_sigmoid(pr);
            float z = fast_sigmoid(pz);
            float nv = fast_tanh(pin + r * phn);
            float hnew = (1.f - z) * nv + z * hv[i];
            hf[(size_t)row * DD + d] = hnew;
            hbc[(size_t)row * DD + d] = (__bf16)hnew;
        }
        __syncthreads();   // (j+1,0) landed; all waves done with buf1
    }
}

// ================= readout =================
__global__ void attn_kernel(const float* __restrict__ hf, const float* __restrict__ w_gate,
                            const float* __restrict__ b_gate, float* __restrict__ attn) {
    int node = blockIdx.x * 4 + (threadIdx.x >> 6);
    int lane = threadIdx.x & 63;
    if (node >= NN) return;
    size_t base = (size_t)node * DD;
    float s = hf[base + lane * 2] * w_gate[lane * 2]
            + hf[base + lane * 2 + 1] * w_gate[lane * 2 + 1];
    for (int off = 32; off; off >>= 1) s += __shfl_down(s, off);
    if (lane == 0) attn[node] = 1.f / (1.f + expf(-(s + b_gate[0])));
}

__global__ void segsum_kernel(const int* __restrict__ goff, const float* __restrict__ attn,
                              const float* __restrict__ hf, float* __restrict__ sg,
                              float* __restrict__ asumg) {
    int g = blockIdx.x;
    int d = threadIdx.x;
    int beg = goff[g], end = goff[g + 1];
    float s = 0.f, asum = 0.f;
    for (int i = beg; i < end; ++i) {
        float a = attn[i];
        s += a * hf[(size_t)i * DD + d];
        if (d == 0) asum += a;
    }
    sg[g * DD + d] = s;
    if (d == 0) asumg[g] = asum;
}

__global__ void readout_kernel(const float* __restrict__ sg, const float* __restrict__ asumg,
                               const float* __restrict__ W_g, const float* __restrict__ b_g,
                               float* __restrict__ hgraph) {
    int g = blockIdx.x;
    int m = threadIdx.x;
    float acc = asumg[g] * b_g[m];
    for (int d = 0; d < DD; ++d) acc += sg[g * DD + d] * W_g[d * GHID + m];
    hgraph[g * GHID + m] = acc;
}

// ================= launch =================
extern "C" void kernel_launch(void* const* d_in, const int* in_sizes, int n_in,
                              void* d_out, int out_size, void* d_ws, size_t ws_size,
                              hipStream_t stream) {
    const int*   node_types = (const int*)d_in[0];
    const int*   edge_src   = (const int*)d_in[1];
    const int*   edge_dst   = (const int*)d_in[2];
    const int*   edge_type  = (const int*)d_in[3];
    const int*   node2graph = (const int*)d_in[4];
    const float* emb        = (const float*)d_in[5];
    const float* W_msg      = (const float*)d_in[6];
    const float* b_msg      = (const float*)d_in[7];
    const float* W_ih       = (const float*)d_in[8];
    const float* W_hh       = (const float*)d_in[9];
    const float* b_ih       = (const float*)d_in[10];
    const float* b_hh       = (const float*)d_in[11];
    const float* w_gate     = (const float*)d_in[12];
    const float* b_gate     = (const float*)d_in[13];
    const float* W_g        = (const float*)d_in[14];
    const float* b_g        = (const float*)d_in[15];

    float* hf     = (float*)d_out;
    float* hgraph = hf + (size_t)NN * DD;

    char* ws = (char*)d_ws;
    size_t off = 0;
    auto alloc = [&](size_t bytes) -> char* {
        char* p = ws + off;
        off += (bytes + 255) & ~(size_t)255;
        return p;
    };
    __bf16* X       = (__bf16*)alloc((size_t)NN * 512 * 2);   // 51.2 MB
    __bf16* hbc     = (__bf16*)alloc((size_t)NN * DD * 2);    // 12.8 MB compact h
    __bf16* WK      = (__bf16*)alloc((size_t)16 * 4 * 256 * 8 * 2);
    __bf16* WB      = (__bf16*)alloc((size_t)12 * 4 * 512 * 8 * 2);
    float*  b512    = (float*)alloc(512 * 4);
    float*  attn    = (float*)alloc((size_t)NN * 4);
    float*  sg      = (float*)alloc((size_t)NG * DD * 4);
    float*  asumg   = (float*)alloc((size_t)NG * 4);
    int*    counts  = (int*)alloc((size_t)(NKEY + 1) * 4);
    int*    offsets = (int*)alloc((size_t)(NKEY + 1) * 4);
    int*    cursor  = (int*)alloc((size_t)(NKEY + 1) * 4);
    int*    bsum    = (int*)alloc((size_t)1024 * 4);
    int*    elist   = (int*)alloc((size_t)NE * 4);
    int*    gcounts = (int*)alloc((size_t)(NG + 1) * 4);
    int*    goff    = (int*)alloc((size_t)(NG + 1) * 4);
    int*    gbsum   = (int*)alloc((size_t)8 * 4);

    hipMemsetAsync(counts, 0, (NKEY + 1) * 4, stream);
    hipMemsetAsync(gcounts, 0, (NG + 1) * 4, stream);

    build_WK<<<(16 * 4 * 256 * 8 + 255) / 256, 256, 0, stream>>>(W_msg, WK);
    build_WBj<<<(12 * 4 * 512 * 8 + 255) / 256, 256, 0, stream>>>(W_ih, W_hh, WB);
    build_bias512<<<2, 256, 0, stream>>>(b_ih, b_hh, b512);
    embed_kernel<<<(NN * DD + 255) / 256, 256, 0, stream>>>(node_types, emb, hf, hbc);

    int nbE = (NKEY + 255) / 256;
    hist_kernel<<<(NE + 255) / 256, 256, 0, stream>>>(edge_src, edge_type, counts);
    scan1<<<nbE, 256, 0, stream>>>(counts, offsets, bsum, NKEY);
    scan2<<<1, 1024, 0, stream>>>(bsum, nbE, offsets, NKEY);
    scan3<<<nbE, 256, 0, stream>>>(offsets, bsum, cursor, NKEY);
    fill_kernel<<<(NE + 255) / 256, 256, 0, stream>>>(edge_src, edge_dst, edge_type, cursor, elist);

    int nbG = (NG + 255) / 256;
    ghist_kernel<<<(NN + 255) / 256, 256, 0, stream>>>(node2graph, gcounts);
    scan1<<<nbG, 256, 0, stream>>>(gcounts, goff, gbsum, NG);
    scan2<<<1, 1024, 0, stream>>>(gbsum, nbG, goff, NG);
    scan3<<<nbG, 256, 0, stream>>>(goff, gbsum, (int*)nullptr, NG);

    int rt2 = (NN + 127) / 128;  // 391
    for (int p = 0; p < NPASS; ++p) {
        agg4<<<(NN + 3) / 4, 256, 0, stream>>>(offsets, elist, hbc, X);
        msgs_gru<<<rt2, 512, 0, stream>>>(X, WK, b_msg, offsets, WB, b512, hf, hbc);
    }

    attn_kernel<<<(NN + 3) / 4, 256, 0, stream>>>(hf, w_gate, b_gate, attn);
    segsum_kernel<<<NG, 128, 0, stream>>>(goff, attn, hf, sg, asumg);
    readout_kernel<<<NG, GHID, 0, stream>>>(sg, asumg, W_g, b_g, hgraph);
}